// Round 16
// baseline (68.895 us; speedup 1.0000x reference)
//
#include <hip/hip_runtime.h>

#define TT 4096

typedef unsigned short u16;
typedef unsigned int u32;

typedef short bf16x8 __attribute__((ext_vector_type(8)));
typedef float f32x4 __attribute__((ext_vector_type(4)));

union U8 {
  uint2 q[2];
  uint4 u4;
  bf16x8 v;
  short s[8];
  u32 w[4];
};

static __device__ __forceinline__ u16 f2bf(float f) {
  union { float f; u32 u; } cv;
  cv.f = f;
  u32 r = cv.u + 0x7FFFu + ((cv.u >> 16) & 1u);
  return (u16)(r >> 16);
}
static __device__ __forceinline__ u32 pk2(float a, float b) {
  return (u32)f2bf(a) | ((u32)f2bf(b) << 16);
}
static __device__ __forceinline__ float exp2a(float x) {
  float r; asm("v_exp_f32 %0, %1" : "=v"(r) : "v"(x)); return r;
}
static __device__ __forceinline__ u32 cvtpk(float lo, float hi) {
  u32 r; asm("v_cvt_pk_bf16_f32 %0, %1, %2" : "=v"(r) : "v"(lo), "v"(hi)); return r;
}

// ---------------------------------------------------------------------------
// Kernel 0: pack W{q,k,v} into MFMA B-fragment layout, bf16.
// ---------------------------------------------------------------------------
__global__ __launch_bounds__(64)
void wpack(const float* __restrict__ Wq, const float* __restrict__ Wk,
           const float* __restrict__ Wv, u16* __restrict__ wf)
{
  const int g = blockIdx.x;              // 0..47
  const int p = g >> 4, s = (g >> 2) & 3, nt = g & 3;
  const int l = threadIdx.x, lg = l >> 4, l15 = l & 15;
  const float* W = (p == 0) ? Wq : (p == 1) ? Wk : Wv;
  const int n = l15 + 16 * nt;
  U8 o;
#pragma unroll
  for (int j = 0; j < 8; ++j) {
    int k = 32 * s + ((j < 4) ? (4 * lg + j) : (16 + 4 * lg + (j - 4)));
    o.s[j] = (short)f2bf(W[k * 64 + n]);
  }
  *(uint4*)(wf + (size_t)(g * 64 + l) * 8) = o.u4;
}

// ---------------------------------------------------------------------------
// Kernel 1: projections via MFMA + LayerNorm. 768 blocks x 256 thr (4 waves).
// v output transposed via LDS then coalesced b128 stores.
// ---------------------------------------------------------------------------
__global__ __launch_bounds__(256)
void proj_mfma(const float* __restrict__ x, const u16* __restrict__ wf,
               const float* __restrict__ bq, const float* __restrict__ bk,
               const float* __restrict__ bv,
               const float* __restrict__ gq, const float* __restrict__ bgq,
               const float* __restrict__ gk, const float* __restrict__ bgk,
               const float* __restrict__ gv, const float* __restrict__ bgv,
               u16* __restrict__ qo, u16* __restrict__ ko, u16* __restrict__ vto,
               float* __restrict__ out)
{
  __shared__ u16 xs[64 * 130];           // 16.25 KB; staging + v-transpose
  const int bx = blockIdx.x;
  const int xcd = bx & 7, i = bx >> 3;
  const int tile = xcd * 32 + (i & 31);  // 0..255
  const int p = i >> 5;                  // 0..2
  const int rowbase = tile * 64;
  const int t = threadIdx.x;

  {
    const int row = t >> 2, seg = t & 3;
    const float4* src = (const float4*)(x + (size_t)(rowbase + row) * 128 + seg * 32);
    float4 f[8];
#pragma unroll
    for (int q = 0; q < 8; ++q) f[q] = src[q];
    if ((p == 0 && seg < 2) || (p == 1 && seg >= 2)) {
      float4* dst = (float4*)(out + (size_t)(rowbase + row) * 192 + seg * 32);
#pragma unroll
      for (int q = 0; q < 8; ++q) dst[q] = f[q];
    }
    const int base = row * 256 + seg * 64;
    const int swz = (row & 7) << 4;
    char* xb = (char*)xs;
#pragma unroll
    for (int q = 0; q < 4; ++q) {
      uint4 u;
      u.x = pk2(f[2 * q].x, f[2 * q].y);
      u.y = pk2(f[2 * q].z, f[2 * q].w);
      u.z = pk2(f[2 * q + 1].x, f[2 * q + 1].y);
      u.w = pk2(f[2 * q + 1].z, f[2 * q + 1].w);
      *(uint4*)(xb + ((base + 16 * q) ^ swz)) = u;
    }
  }

  const int w = t >> 6, l = t & 63, lg = l >> 4, l15 = l & 15;
  U8 bfr[4][4];
  const u16* wp = wf + (size_t)p * (16 * 64 * 8);
#pragma unroll
  for (int s = 0; s < 4; ++s)
#pragma unroll
    for (int nt = 0; nt < 4; ++nt)
      bfr[s][nt].u4 = *(const uint4*)(wp + ((s * 4 + nt) * 64 + l) * 8);

  __syncthreads();

  f32x4 acc[4];
#pragma unroll
  for (int nt = 0; nt < 4; ++nt) acc[nt] = (f32x4){0.f, 0.f, 0.f, 0.f};
  const int abase = (16 * w + l15) * 256;
  const int aswz = (l15 & 7) << 4;
  const char* xb = (const char*)xs;
#pragma unroll
  for (int s = 0; s < 4; ++s) {
    U8 af;
    af.q[0] = *(const uint2*)(xb + ((abase + s * 64 + 8 * lg) ^ aswz));
    af.q[1] = *(const uint2*)(xb + ((abase + s * 64 + 8 * lg + 32) ^ aswz));
#pragma unroll
    for (int nt = 0; nt < 4; ++nt)
      acc[nt] = __builtin_amdgcn_mfma_f32_16x16x32_bf16(af.v, bfr[s][nt].v, acc[nt], 0, 0, 0);
  }

  const float* bb = (p == 0) ? bq : (p == 1) ? bk : bv;
  const float* gg = (p == 0) ? gq : (p == 1) ? gk : gv;
  const float* hh = (p == 0) ? bgq : (p == 1) ? bgk : bgv;
  float bcol[4], gcol[4], hcol[4];
#pragma unroll
  for (int nt = 0; nt < 4; ++nt) {
    int col = l15 + 16 * nt;
    bcol[nt] = bb[col]; gcol[nt] = gg[col]; hcol[nt] = hh[col];
  }
  float vals[4][4];
#pragma unroll
  for (int nt = 0; nt < 4; ++nt)
#pragma unroll
    for (int r = 0; r < 4; ++r) vals[nt][r] = acc[nt][r] + bcol[nt];

  float s1[4], s2[4];
#pragma unroll
  for (int r = 0; r < 4; ++r) {
    s1[r] = vals[0][r] + vals[1][r] + vals[2][r] + vals[3][r];
    s2[r] = vals[0][r] * vals[0][r] + vals[1][r] * vals[1][r]
          + vals[2][r] * vals[2][r] + vals[3][r] * vals[3][r];
#pragma unroll
    for (int d = 1; d < 16; d <<= 1) {
      s1[r] += __shfl_xor(s1[r], d);
      s2[r] += __shfl_xor(s2[r], d);
    }
  }

  if (p < 2) {
    u16* dst = (p == 0) ? qo : ko;
#pragma unroll
    for (int r = 0; r < 4; ++r) {
      float mu = s1[r] * (1.f / 64.f);
      float var = s2[r] * (1.f / 64.f) - mu * mu;
      float rs = rsqrtf(var + 1e-5f);
      int grow = rowbase + 16 * w + 4 * lg + r;
#pragma unroll
      for (int nt = 0; nt < 4; ++nt)
        dst[(size_t)grow * 64 + l15 + 16 * nt] =
            f2bf((vals[nt][r] - mu) * rs * gcol[nt] + hcol[nt]);
    }
  } else {
    // v: LDS transpose (stride-65 pad) then coalesced stores
    u16* vls = xs;
    __syncthreads();                      // all A-frag reads done
#pragma unroll
    for (int r = 0; r < 4; ++r) {
      float mu = s1[r] * (1.f / 64.f);
      float var = s2[r] * (1.f / 64.f) - mu * mu;
      float rs = rsqrtf(var + 1e-5f);
      int row = 16 * w + 4 * lg + r;
#pragma unroll
      for (int nt = 0; nt < 4; ++nt)
        vls[row * 65 + l15 + 16 * nt] =
            f2bf((vals[nt][r] - mu) * rs * gcol[nt] + hcol[nt]);
    }
    __syncthreads();
    const int b = rowbase >> 12;
    const int tl = rowbase & 4095;
    const int col = t >> 2;               // 0..63
    const int tq = (t & 3) * 16;          // row offset 0,16,32,48
    U8 o0, o1;
#pragma unroll
    for (int i = 0; i < 8; ++i) o0.s[i] = (short)vls[(tq + i) * 65 + col];
#pragma unroll
    for (int i = 0; i < 8; ++i) o1.s[i] = (short)vls[(tq + 8 + i) * 65 + col];
    u16* dst = vto + (size_t)(b * 64 + col) * TT + tl + tq;
    *(uint4*)(dst + 0) = o0.u4;
    *(uint4*)(dst + 8) = o1.u4;
  }
}

// ---------------------------------------------------------------------------
// Kernel 2a: paired-qtile W=4 segment, NO-MAX softmax, branch-free chains
// (byte-identical body to the proven pair4n), ATOMIC-SUM tail: partials are
// accumulated into global f32 (o,l) sum buffers (merge is a pure sum by
// softmax shift-invariance) -> merge kernel + 36 MB partial traffic deleted.
// ---------------------------------------------------------------------------
__global__ __launch_bounds__(256)
void attn_pair4a(const u16* __restrict__ qg, const u16* __restrict__ kg,
                 const u16* __restrict__ vtg,
                 float* __restrict__ oSum, float* __restrict__ lSum)
{
  __shared__ u16 kl4[4 * 64 * 64];
  __shared__ u16 vl4[4 * 64 * 64];
  const int bx = blockIdx.x;
  const int xcd = bx & 7, b = xcd >> 1, e2 = xcd & 1;
  const int j = e2 * 136 + (bx >> 3);     // 0..271
  int M = 0;
  while ((M + 1) * (M + 2) <= j) ++M;     // group M = pairs {2M, 2M+1}
  const int ip = j - M * (M + 1);
  const int e = (ip >= M + 1) ? 1 : 0;
  const int s = ip - e * (M + 1);
  const int pr = 2 * M + e;               // pair 0..31
  const int qa = 2 * pr, qb = 2 * pr + 1;
  const int it0 = 4 * s;
  const int it1 = min(it0 + 4, qb + 1);

  const int t = threadIdx.x;
  const int w = t >> 6, l = t & 63;
  const int l15 = l & 15, lg = l >> 4;
  const int swzl = (l15 & 7) << 4;

  const int wbaseA = qa * 64 + 16 * w, wbaseB = qb * 64 + 16 * w;
  const int qrowA = wbaseA + l15, qrowB = wbaseB + l15;
  const u16* qrpA = qg + (size_t)(b * TT + qrowA) * 64;
  const u16* qrpB = qg + (size_t)(b * TT + qrowB) * 64;
  U8 qfA[2], qfB[2];
#pragma unroll
  for (int hh = 0; hh < 2; ++hh) {
    qfA[hh].q[0] = *(const uint2*)(qrpA + 32 * hh + 4 * lg);
    qfA[hh].q[1] = *(const uint2*)(qrpA + 32 * hh + 4 * lg + 16);
    qfB[hh].q[0] = *(const uint2*)(qrpB + 32 * hh + 4 * lg);
    qfB[hh].q[1] = *(const uint2*)(qrpB + 32 * hh + 4 * lg + 16);
  }

  // ---- stage the whole segment (coalesced), one barrier ----
  {
    const int key = t >> 2, part = t & 3;
    const int sbase = key * 128 + part * 32;
    const int ssw = (key & 7) << 4;
    uint4 kr[4][2], vr[4][2];
#pragma unroll
    for (int tt = 0; tt < 4; ++tt) {
      int tile = it0 + tt; if (tile >= it1) tile = it1 - 1;
      const u16* ks = kg + (size_t)(b * TT + tile * 64 + key) * 64 + part * 16;
      kr[tt][0] = ((const uint4*)ks)[0];
      kr[tt][1] = ((const uint4*)ks)[1];
      const u16* vs = vtg + (size_t)(b * 64 + key) * TT + tile * 64 + part * 16;
      vr[tt][0] = ((const uint4*)vs)[0];
      vr[tt][1] = ((const uint4*)vs)[1];
    }
#pragma unroll
    for (int tt = 0; tt < 4; ++tt) {
      char* kd = (char*)kl4 + tt * 8192;
      char* vd = (char*)vl4 + tt * 8192;
      *(uint4*)(kd + ((sbase + 0) ^ ssw)) = kr[tt][0];
      *(uint4*)(kd + ((sbase + 16) ^ ssw)) = kr[tt][1];
      *(uint4*)(vd + ((sbase + 0) ^ ssw)) = vr[tt][0];
      *(uint4*)(vd + ((sbase + 16) ^ ssw)) = vr[tt][1];
    }
  }
  __syncthreads();

  const float C = 0.18033688011112042f;   // log2(e)/sqrt(64)
  float lA = 0.f, lB = 0.f;
  f32x4 accA[4], accB[4];
#pragma unroll
  for (int ct = 0; ct < 4; ++ct) {
    accA[ct] = (f32x4){0.f, 0.f, 0.f, 0.f};
    accB[ct] = (f32x4){0.f, 0.f, 0.f, 0.f};
  }

  int toff = 0;
  for (int it = it0; it < it1; ++it, toff += 8192) {
    const int kb = it * 64;
    const char* kp = (const char*)kl4 + toff;
    const char* vp = (const char*)vl4 + toff;

    // ---- QK for both chains; each kf read feeds 4 MFMAs ----
    f32x4 stA[4], stB[4];
    __builtin_amdgcn_s_setprio(1);
#pragma unroll
    for (int t4 = 0; t4 < 4; ++t4) {
      const int rbase = (16 * t4 + l15) * 128 + 8 * lg;
      U8 kf0, kf1;
      kf0.q[0] = *(const uint2*)(kp + ((rbase + 0) ^ swzl));
      kf0.q[1] = *(const uint2*)(kp + ((rbase + 32) ^ swzl));
      kf1.q[0] = *(const uint2*)(kp + ((rbase + 64) ^ swzl));
      kf1.q[1] = *(const uint2*)(kp + ((rbase + 96) ^ swzl));
      f32x4 dA = {0.f, 0.f, 0.f, 0.f};
      dA = __builtin_amdgcn_mfma_f32_16x16x32_bf16(kf0.v, qfA[0].v, dA, 0, 0, 0);
      dA = __builtin_amdgcn_mfma_f32_16x16x32_bf16(kf1.v, qfA[1].v, dA, 0, 0, 0);
      stA[t4] = dA;
      f32x4 dB = {0.f, 0.f, 0.f, 0.f};
      dB = __builtin_amdgcn_mfma_f32_16x16x32_bf16(kf0.v, qfB[0].v, dB, 0, 0, 0);
      dB = __builtin_amdgcn_mfma_f32_16x16x32_bf16(kf1.v, qfB[1].v, dB, 0, 0, 0);
      stB[t4] = dB;
    }
    __builtin_amdgcn_s_setprio(0);

    // ---- no-max softmax, both chains (independent straight-line code) ----
    float pA[16], pB[16];
    const bool maskA = (kb + 63 > wbaseA);
    if (maskA) {
#pragma unroll
      for (int t4 = 0; t4 < 4; ++t4) {
#pragma unroll
        for (int r = 0; r < 4; ++r) {
          int keyidx = kb + 16 * t4 + 4 * lg + r;
          float e = exp2a(stA[t4][r] * C);
          pA[t4 * 4 + r] = (keyidx > qrowA) ? 0.f : e;
        }
      }
    } else {
#pragma unroll
      for (int t4 = 0; t4 < 4; ++t4) {
#pragma unroll
        for (int r = 0; r < 4; ++r) pA[t4 * 4 + r] = exp2a(stA[t4][r] * C);
      }
    }
    const bool maskB = (kb + 63 > wbaseB);
    if (maskB) {
#pragma unroll
      for (int t4 = 0; t4 < 4; ++t4) {
#pragma unroll
        for (int r = 0; r < 4; ++r) {
          int keyidx = kb + 16 * t4 + 4 * lg + r;
          float e = exp2a(stB[t4][r] * C);
          pB[t4 * 4 + r] = (keyidx > qrowB) ? 0.f : e;
        }
      }
    } else {
#pragma unroll
      for (int t4 = 0; t4 < 4; ++t4) {
#pragma unroll
        for (int r = 0; r < 4; ++r) pB[t4 * 4 + r] = exp2a(stB[t4][r] * C);
      }
    }
    float smA[8], smB[8];
#pragma unroll
    for (int i = 0; i < 8; ++i) {
      smA[i] = pA[2 * i] + pA[2 * i + 1];
      smB[i] = pB[2 * i] + pB[2 * i + 1];
    }
#pragma unroll
    for (int i = 0; i < 4; ++i) {
      smA[i] = smA[2 * i] + smA[2 * i + 1];
      smB[i] = smB[2 * i] + smB[2 * i + 1];
    }
    float rsA = (smA[0] + smA[1]) + (smA[2] + smA[3]);
    float rsB = (smB[0] + smB[1]) + (smB[2] + smB[3]);
    rsA += __shfl_xor(rsA, 16);
    rsB += __shfl_xor(rsB, 16);
    rsA += __shfl_xor(rsA, 32);
    rsB += __shfl_xor(rsB, 32);
    lA += rsA;
    lB += rsB;

    U8 paA[2], paB[2];
#pragma unroll
    for (int u = 0; u < 2; ++u) {
#pragma unroll
      for (int k2 = 0; k2 < 4; ++k2) {
        paA[u].w[k2] = cvtpk(pA[8 * u + 2 * k2], pA[8 * u + 2 * k2 + 1]);
        paB[u].w[k2] = cvtpk(pB[8 * u + 2 * k2], pB[8 * u + 2 * k2 + 1]);
      }
    }

    // ---- PV for both chains; each vf read feeds 2 MFMAs ----
    __builtin_amdgcn_s_setprio(1);
#pragma unroll
    for (int ct = 0; ct < 4; ++ct) {
      const int vb = (16 * ct + l15) * 128 + 8 * lg;
#pragma unroll
      for (int u = 0; u < 2; ++u) {
        U8 vf;
        vf.q[0] = *(const uint2*)(vp + ((vb + 64 * u + 0) ^ swzl));
        vf.q[1] = *(const uint2*)(vp + ((vb + 64 * u + 32) ^ swzl));
        accA[ct] = __builtin_amdgcn_mfma_f32_16x16x32_bf16(paA[u].v, vf.v, accA[ct], 0, 0, 0);
        accB[ct] = __builtin_amdgcn_mfma_f32_16x16x32_bf16(paB[u].v, vf.v, accB[ct], 0, 0, 0);
      }
    }
    __builtin_amdgcn_s_setprio(0);
  }

  // ---- atomic-sum tail: accumulate (o,l) into global f32 buffers ----
  if (lg == 0) {
    atomicAdd(&lSum[b * TT + wbaseA + l15], lA);
    atomicAdd(&lSum[b * TT + wbaseB + l15], lB);
  }
#pragma unroll
  for (int ct = 0; ct < 4; ++ct) {
#pragma unroll
    for (int r = 0; r < 4; ++r) {
      int rin = 16 * w + 4 * lg + r;
      atomicAdd(&oSum[((size_t)(b * TT + qa * 64 + rin)) * 64 + l15 + 16 * ct], accA[ct][r]);
      atomicAdd(&oSum[((size_t)(b * TT + qb * 64 + rin)) * 64 + l15 + 16 * ct], accB[ct][r]);
    }
  }
}

// ---------------------------------------------------------------------------
// Kernel 2b: LN finish — read summed (o,l), normalize, LayerNorm, store.
// 4096 blocks x 256 thr; wave = one row.
// ---------------------------------------------------------------------------
__global__ __launch_bounds__(256)
void attn_lnfin(const float* __restrict__ oSum, const float* __restrict__ lSum,
                const float* __restrict__ go, const float* __restrict__ bgo,
                float* __restrict__ out)
{
  const int t = threadIdx.x;
  const int w = t >> 6, c = t & 63;
  const int row = blockIdx.x * 4 + w;       // 0..16383
  float o = oSum[(size_t)row * 64 + c] / lSum[row];

  float s1 = o, s2 = o * o;
#pragma unroll
  for (int d = 1; d < 64; d <<= 1) {
    s1 += __shfl_xor(s1, d);
    s2 += __shfl_xor(s2, d);
  }
  float mu = s1 * (1.f / 64.f);
  float var = s2 * (1.f / 64.f) - mu * mu;
  float rs = rsqrtf(var + 1e-5f);
  out[(size_t)row * 192 + 128 + c] = (o - mu) * rs * go[c] + bgo[c];
}

// ---------------------------------------------------------------------------
// Kernel 2 last-resort fallback: single-pass LDS attn (round 2 proven).
// ---------------------------------------------------------------------------
__global__ __launch_bounds__(128)
void attn1(const u16* __restrict__ qg, const u16* __restrict__ kg,
           const u16* __restrict__ vtg,
           const float* __restrict__ go, const float* __restrict__ bgo,
           float* __restrict__ out)
{
  __shared__ u16 kl[64 * 64];
  __shared__ u16 vl[64 * 64];
  const int bx = blockIdx.x;
  const int tt = (bx < 256) ? bx : (767 - bx);
  const int b = tt >> 7;
  const int q0 = (tt & 127) * 32;
  const int tid = threadIdx.x;
  const int w = tid >> 6;
  const int l = tid & 63;
  const int l15 = l & 15;
  const int lg = l >> 4;
  const int swzl = (l15 & 7) << 4;

  const int qrow = q0 + 16 * w + l15;
  const u16* qrp = qg + (size_t)(b * TT + qrow) * 64;
  U8 qf[2];
#pragma unroll
  for (int h = 0; h < 2; ++h) {
    qf[h].q[0] = *(const uint2*)(qrp + 32 * h + 4 * lg);
    qf[h].q[1] = *(const uint2*)(qrp + 32 * h + 4 * lg + 16);
  }

  float m_run = -1e30f, l_run = 0.f;
  f32x4 acc[4];
#pragma unroll
  for (int ct = 0; ct < 4; ++ct) acc[ct] = (f32x4){0.f, 0.f, 0.f, 0.f};

  const int nkv = (q0 >> 6) + 1;
  for (int it = 0; it < nkv; ++it) {
    const int kb = it * 64;
    {
      const int key = tid >> 1;
      const int dh = (tid & 1) * 32;
      const u16* ks = kg + (size_t)(b * TT + kb + key) * 64 + dh;
      uint4 d0 = *(const uint4*)(ks + 0);
      uint4 d1 = *(const uint4*)(ks + 8);
      uint4 d2 = *(const uint4*)(ks + 16);
      uint4 d3 = *(const uint4*)(ks + 24);
      const int base = key * 128 + dh * 2;
      const int sw = (key & 7) << 4;
      char* kd = (char*)kl;
      *(uint4*)(kd + ((base + 0) ^ sw)) = d0;
      *(uint4*)(kd + ((base + 16) ^ sw)) = d1;
      *(uint4*)(kd + ((base + 32) ^ sw)) = d2;
      *(uint4*)(kd + ((base + 48) ^ sw)) = d3;
      const u16* vs = vtg + (size_t)(b * 64 + key) * TT + kb + dh;
      uint4 e0 = *(const uint4*)(vs + 0);
      uint4 e1 = *(const uint4*)(vs + 8);
      uint4 e2 = *(const uint4*)(vs + 16);
      uint4 e3 = *(const uint4*)(vs + 24);
      char* vd = (char*)vl;
      *(uint4*)(vd + ((base + 0) ^ sw)) = e0;
      *(uint4*)(vd + ((base + 16) ^ sw)) = e1;
      *(uint4*)(vd + ((base + 32) ^ sw)) = e2;
      *(uint4*)(vd + ((base + 48) ^ sw)) = e3;
    }
    __syncthreads();

    f32x4 st[4];
#pragma unroll
    for (int t4 = 0; t4 < 4; ++t4) {
      const int rbase = (16 * t4 + l15) * 128 + 8 * lg;
      const char* kp = (const char*)kl;
      U8 kf0, kf1;
      kf0.q[0] = *(const uint2*)(kp + ((rbase + 0) ^ swzl));
      kf0.q[1] = *(const uint2*)(kp + ((rbase + 32) ^ swzl));
      kf1.q[0] = *(const uint2*)(kp + ((rbase + 64) ^ swzl));
      kf1.q[1] = *(const uint2*)(kp + ((rbase + 96) ^ swzl));
      f32x4 d = {0.f, 0.f, 0.f, 0.f};
      d = __builtin_amdgcn_mfma_f32_16x16x32_bf16(kf0.v, qf[0].v, d, 0, 0, 0);
      d = __builtin_amdgcn_mfma_f32_16x16x32_bf16(kf1.v, qf[1].v, d, 0, 0, 0);
      st[t4] = d;
    }

    float sv[16];
    const bool needmask = (kb + 63 > q0 + 16 * w);
#pragma unroll
    for (int t4 = 0; t4 < 4; ++t4) {
#pragma unroll
      for (int r = 0; r < 4; ++r) {
        float sc = st[t4][r] * 0.125f;
        if (needmask) {
          int keyidx = kb + 16 * t4 + 4 * lg + r;
          if (keyidx > qrow) sc = -1e30f;
        }
        sv[t4 * 4 + r] = sc;
      }
    }
    float mt = sv[0];
#pragma unroll
    for (int i = 1; i < 16; ++i) mt = fmaxf(mt, sv[i]);
    mt = fmaxf(mt, __shfl_xor(mt, 16));
    mt = fmaxf(mt, __shfl_xor(mt, 32));
    const float mnew = fmaxf(m_run, mt);
    const float al = __expf(m_run - mnew);
    float p[16];
    float rsum = 0.f;
#pragma unroll
    for (int i = 0; i < 16; ++i) { p[i] = __expf(sv[i] - mnew); rsum += p[i]; }
    rsum += __shfl_xor(rsum, 16);
    rsum += __shfl_xor(rsum, 32);
    l_run = l_run * al + rsum;
    m_run = mnew;
    float ar[4];
#pragma unroll
    for (int r = 0; r < 4; ++r) ar[r] = __shfl(al, 4 * lg + r);
#pragma unroll
    for (int ct = 0; ct < 4; ++ct) {
#pragma unroll
      for (int r = 0; r < 4; ++r) acc[ct][r] *= ar[r];
    }
    U8 pa[2];
#pragma unroll
    for (int u = 0; u < 2; ++u) {
#pragma unroll
      for (int i = 0; i < 8; ++i) pa[u].s[i] = (short)f2bf(p[8 * u + i]);
    }

#pragma unroll
    for (int ct = 0; ct < 4; ++ct) {
      const int vb = (16 * ct + l15) * 128 + 8 * lg;
      const char* vp = (const char*)vl;
#pragma unroll
      for (int u = 0; u < 2; ++u) {
        U8 vf;
        vf.q[0] = *(const uint2*)(vp + ((vb + 64 * u + 0) ^ swzl));
        vf.q[1] = *(const uint2*)(vp + ((vb + 64 * u + 32) ^ swzl));
        acc[ct] = __builtin_amdgcn_mfma_f32_16x16x32_bf16(pa[u].v, vf.v, acc[ct], 0, 0, 0);
      }
    }
    __syncthreads();
  }

  float linv[4];
#pragma unroll
  for (int r = 0; r < 4; ++r) linv[r] = 1.f / __shfl(l_run, 4 * lg + r);
  float o[4][4];
#pragma unroll
  for (int ct = 0; ct < 4; ++ct) {
#pragma unroll
    for (int r = 0; r < 4; ++r) o[ct][r] = acc[ct][r] * linv[r];
  }
  float s1[4], s2[4];
#pragma unroll
  for (int r = 0; r < 4; ++r) {
    s1[r] = o[0][r] + o[1][r] + o[2][r] + o[3][r];
    s2[r] = o[0][r] * o[0][r] + o[1][r] * o[1][r] + o[2][r] * o[2][r] + o[3][r] * o[3][r];
#pragma unroll
    for (int d = 1; d < 16; d <<= 1) {
      s1[r] += __shfl_xor(s1[r], d);
      s2[r] += __shfl_xor(s2[r], d);
    }
  }
  float gov[4], bgv2[4];
#pragma unroll
  for (int ct = 0; ct < 4; ++ct) {
    gov[ct] = go[16 * ct + l15];
    bgv2[ct] = bgo[16 * ct + l15];
  }
#pragma unroll
  for (int r = 0; r < 4; ++r) {
    float mu = s1[r] * (1.f / 64.f);
    float var = s2[r] * (1.f / 64.f) - mu * mu;
    float rs = rsqrtf(var + 1e-5f);
    int row = q0 + 16 * w + 4 * lg + r;
    float* op = out + (size_t)(b * TT + row) * 192 + 128;
#pragma unroll
    for (int ct = 0; ct < 4; ++ct)
      op[16 * ct + l15] = (o[ct][r] - mu) * rs * gov[ct] + bgv2[ct];
  }
}

extern "C" void kernel_launch(void* const* d_in, const int* in_sizes, int n_in,
                              void* d_out, int out_size, void* d_ws, size_t ws_size,
                              hipStream_t stream) {
  (void)in_sizes; (void)n_in; (void)out_size;
  const float* x   = (const float*)d_in[0];
  const float* Wq  = (const float*)d_in[1];
  const float* bq  = (const float*)d_in[2];
  const float* Wk  = (const float*)d_in[3];
  const float* bk  = (const float*)d_in[4];
  const float* Wv  = (const float*)d_in[5];
  const float* bv  = (const float*)d_in[6];
  const float* gq  = (const float*)d_in[7];
  const float* bgq = (const float*)d_in[8];
  const float* gk  = (const float*)d_in[9];
  const float* bgk = (const float*)d_in[10];
  const float* gv  = (const float*)d_in[11];
  const float* bgv = (const float*)d_in[12];
  const float* go  = (const float*)d_in[13];
  const float* bgo = (const float*)d_in[14];
  float* out = (float*)d_out;

  // ws layout: q 2MB | k 2MB | vt 2MB | wfr 64KB | oSum 4MB | lSum 64KB
  char* wsb = (char*)d_ws;
  u16* qws  = (u16*)wsb;
  u16* kws  = (u16*)(wsb + (2u << 20));
  u16* vtws = (u16*)(wsb + (4u << 20));
  u16* wfr  = (u16*)(wsb + (6u << 20));
  const size_t OFF_OS = (6u << 20) + 65536;
  const size_t OSZ = (size_t)4 * TT * 64 * 4;       // 4,194,304
  const size_t LSZ = (size_t)4 * TT * 4;            // 65,536
  const size_t NEED = OFF_OS + OSZ + LSZ;           // ~10.6 MB
  float* oSum = (float*)(wsb + OFF_OS);
  float* lSum = (float*)(wsb + OFF_OS + OSZ);

  wpack<<<48, 64, 0, stream>>>(Wq, Wk, Wv, wfr);
  proj_mfma<<<768, 256, 0, stream>>>(x, wfr, bq, bk, bv,
                                     gq, bgq, gk, bgk, gv, bgv,
                                     qws, kws, vtws, out);

  if (ws_size >= NEED) {
    hipMemsetAsync(wsb + OFF_OS, 0, OSZ + LSZ, stream);
    attn_pair4a<<<1088, 256, 0, stream>>>(qws, kws, vtws, oSum, lSum);
    attn_lnfin<<<4096, 256, 0, stream>>>(oSum, lSum, go, bgo, out);
  } else {
    attn1<<<512, 128, 0, stream>>>(qws, kws, vtws, go, bgo, out);
  }
}

// Round 17
// 67.843 us; speedup vs baseline: 1.0155x; 1.0155x over previous
//
#include <hip/hip_runtime.h>

#define TT 4096

typedef unsigned short u16;
typedef unsigned int u32;

typedef short bf16x8 __attribute__((ext_vector_type(8)));
typedef float f32x4 __attribute__((ext_vector_type(4)));

union U8 {
  uint2 q[2];
  uint4 u4;
  bf16x8 v;
  short s[8];
  u32 w[4];
};

static __device__ __forceinline__ u16 f2bf(float f) {
  union { float f; u32 u; } cv;
  cv.f = f;
  u32 r = cv.u + 0x7FFFu + ((cv.u >> 16) & 1u);
  return (u16)(r >> 16);
}
static __device__ __forceinline__ u32 pk2(float a, float b) {
  return (u32)f2bf(a) | ((u32)f2bf(b) << 16);
}
static __device__ __forceinline__ float bf2f(u16 h) {
  union { u32 u; float f; } cv;
  cv.u = ((u32)h) << 16;
  return cv.f;
}
static __device__ __forceinline__ float exp2a(float x) {
  float r; asm("v_exp_f32 %0, %1" : "=v"(r) : "v"(x)); return r;
}
static __device__ __forceinline__ u32 cvtpk(float lo, float hi) {
  u32 r; asm("v_cvt_pk_bf16_f32 %0, %1, %2" : "=v"(r) : "v"(lo), "v"(hi)); return r;
}

// ---------------------------------------------------------------------------
// Kernel 0: pack W{q,k,v} into MFMA B-fragment layout, bf16.
// ---------------------------------------------------------------------------
__global__ __launch_bounds__(64)
void wpack(const float* __restrict__ Wq, const float* __restrict__ Wk,
           const float* __restrict__ Wv, u16* __restrict__ wf)
{
  const int g = blockIdx.x;              // 0..47
  const int p = g >> 4, s = (g >> 2) & 3, nt = g & 3;
  const int l = threadIdx.x, lg = l >> 4, l15 = l & 15;
  const float* W = (p == 0) ? Wq : (p == 1) ? Wk : Wv;
  const int n = l15 + 16 * nt;
  U8 o;
#pragma unroll
  for (int j = 0; j < 8; ++j) {
    int k = 32 * s + ((j < 4) ? (4 * lg + j) : (16 + 4 * lg + (j - 4)));
    o.s[j] = (short)f2bf(W[k * 64 + n]);
  }
  *(uint4*)(wf + (size_t)(g * 64 + l) * 8) = o.u4;
}

// ---------------------------------------------------------------------------
// Kernel 1: projections via MFMA + LayerNorm. 768 blocks x 256 thr (4 waves).
// v output transposed via LDS then coalesced b128 stores.
// ---------------------------------------------------------------------------
__global__ __launch_bounds__(256)
void proj_mfma(const float* __restrict__ x, const u16* __restrict__ wf,
               const float* __restrict__ bq, const float* __restrict__ bk,
               const float* __restrict__ bv,
               const float* __restrict__ gq, const float* __restrict__ bgq,
               const float* __restrict__ gk, const float* __restrict__ bgk,
               const float* __restrict__ gv, const float* __restrict__ bgv,
               u16* __restrict__ qo, u16* __restrict__ ko, u16* __restrict__ vto,
               float* __restrict__ out)
{
  __shared__ u16 xs[64 * 130];           // 16.25 KB; staging + v-transpose
  const int bx = blockIdx.x;
  const int xcd = bx & 7, i = bx >> 3;
  const int tile = xcd * 32 + (i & 31);  // 0..255
  const int p = i >> 5;                  // 0..2
  const int rowbase = tile * 64;
  const int t = threadIdx.x;

  {
    const int row = t >> 2, seg = t & 3;
    const float4* src = (const float4*)(x + (size_t)(rowbase + row) * 128 + seg * 32);
    float4 f[8];
#pragma unroll
    for (int q = 0; q < 8; ++q) f[q] = src[q];
    if ((p == 0 && seg < 2) || (p == 1 && seg >= 2)) {
      float4* dst = (float4*)(out + (size_t)(rowbase + row) * 192 + seg * 32);
#pragma unroll
      for (int q = 0; q < 8; ++q) dst[q] = f[q];
    }
    const int base = row * 256 + seg * 64;
    const int swz = (row & 7) << 4;
    char* xb = (char*)xs;
#pragma unroll
    for (int q = 0; q < 4; ++q) {
      uint4 u;
      u.x = pk2(f[2 * q].x, f[2 * q].y);
      u.y = pk2(f[2 * q].z, f[2 * q].w);
      u.z = pk2(f[2 * q + 1].x, f[2 * q + 1].y);
      u.w = pk2(f[2 * q + 1].z, f[2 * q + 1].w);
      *(uint4*)(xb + ((base + 16 * q) ^ swz)) = u;
    }
  }

  const int w = t >> 6, l = t & 63, lg = l >> 4, l15 = l & 15;
  U8 bfr[4][4];
  const u16* wp = wf + (size_t)p * (16 * 64 * 8);
#pragma unroll
  for (int s = 0; s < 4; ++s)
#pragma unroll
    for (int nt = 0; nt < 4; ++nt)
      bfr[s][nt].u4 = *(const uint4*)(wp + ((s * 4 + nt) * 64 + l) * 8);

  __syncthreads();

  f32x4 acc[4];
#pragma unroll
  for (int nt = 0; nt < 4; ++nt) acc[nt] = (f32x4){0.f, 0.f, 0.f, 0.f};
  const int abase = (16 * w + l15) * 256;
  const int aswz = (l15 & 7) << 4;
  const char* xb = (const char*)xs;
#pragma unroll
  for (int s = 0; s < 4; ++s) {
    U8 af;
    af.q[0] = *(const uint2*)(xb + ((abase + s * 64 + 8 * lg) ^ aswz));
    af.q[1] = *(const uint2*)(xb + ((abase + s * 64 + 8 * lg + 32) ^ aswz));
#pragma unroll
    for (int nt = 0; nt < 4; ++nt)
      acc[nt] = __builtin_amdgcn_mfma_f32_16x16x32_bf16(af.v, bfr[s][nt].v, acc[nt], 0, 0, 0);
  }

  const float* bb = (p == 0) ? bq : (p == 1) ? bk : bv;
  const float* gg = (p == 0) ? gq : (p == 1) ? gk : gv;
  const float* hh = (p == 0) ? bgq : (p == 1) ? bgk : bgv;
  float bcol[4], gcol[4], hcol[4];
#pragma unroll
  for (int nt = 0; nt < 4; ++nt) {
    int col = l15 + 16 * nt;
    bcol[nt] = bb[col]; gcol[nt] = gg[col]; hcol[nt] = hh[col];
  }
  float vals[4][4];
#pragma unroll
  for (int nt = 0; nt < 4; ++nt)
#pragma unroll
    for (int r = 0; r < 4; ++r) vals[nt][r] = acc[nt][r] + bcol[nt];

  float s1[4], s2[4];
#pragma unroll
  for (int r = 0; r < 4; ++r) {
    s1[r] = vals[0][r] + vals[1][r] + vals[2][r] + vals[3][r];
    s2[r] = vals[0][r] * vals[0][r] + vals[1][r] * vals[1][r]
          + vals[2][r] * vals[2][r] + vals[3][r] * vals[3][r];
#pragma unroll
    for (int d = 1; d < 16; d <<= 1) {
      s1[r] += __shfl_xor(s1[r], d);
      s2[r] += __shfl_xor(s2[r], d);
    }
  }

  if (p < 2) {
    u16* dst = (p == 0) ? qo : ko;
#pragma unroll
    for (int r = 0; r < 4; ++r) {
      float mu = s1[r] * (1.f / 64.f);
      float var = s2[r] * (1.f / 64.f) - mu * mu;
      float rs = rsqrtf(var + 1e-5f);
      int grow = rowbase + 16 * w + 4 * lg + r;
#pragma unroll
      for (int nt = 0; nt < 4; ++nt)
        dst[(size_t)grow * 64 + l15 + 16 * nt] =
            f2bf((vals[nt][r] - mu) * rs * gcol[nt] + hcol[nt]);
    }
  } else {
    // v: LDS transpose (stride-65 pad) then coalesced stores
    u16* vls = xs;
    __syncthreads();                      // all A-frag reads done
#pragma unroll
    for (int r = 0; r < 4; ++r) {
      float mu = s1[r] * (1.f / 64.f);
      float var = s2[r] * (1.f / 64.f) - mu * mu;
      float rs = rsqrtf(var + 1e-5f);
      int row = 16 * w + 4 * lg + r;
#pragma unroll
      for (int nt = 0; nt < 4; ++nt)
        vls[row * 65 + l15 + 16 * nt] =
            f2bf((vals[nt][r] - mu) * rs * gcol[nt] + hcol[nt]);
    }
    __syncthreads();
    const int b = rowbase >> 12;
    const int tl = rowbase & 4095;
    const int col = t >> 2;               // 0..63
    const int tq = (t & 3) * 16;          // row offset 0,16,32,48
    U8 o0, o1;
#pragma unroll
    for (int i = 0; i < 8; ++i) o0.s[i] = (short)vls[(tq + i) * 65 + col];
#pragma unroll
    for (int i = 0; i < 8; ++i) o1.s[i] = (short)vls[(tq + 8 + i) * 65 + col];
    u16* dst = vto + (size_t)(b * 64 + col) * TT + tl + tq;
    *(uint4*)(dst + 0) = o0.u4;
    *(uint4*)(dst + 8) = o1.u4;
  }
}

// ---------------------------------------------------------------------------
// Kernel 2a: paired-qtile W=2 segment, NO-MAX softmax, branch-free chains,
// shared kf/vf reads (proven pair4n body) at 32 KB LDS -> 4 blocks/CU
// (2x pair4n's co-residency; no __launch_bounds__ forcing, VGPR ~100).
// Every block runs exactly 2 uniform iterations (no tail).
// Group M = pairs {2M,2M+1}; group start = 2M^2+M (528 segs per half-batch).
// Partials: l (f32) + unnormalized acc (bf16), per-qtile compact slots
// (base Q(Q+1)+(q&1)(Q+1), 1056/batch); merge is a pure sum.
// ---------------------------------------------------------------------------
__global__ __launch_bounds__(256)
void attn_pair2n(const u16* __restrict__ qg, const u16* __restrict__ kg,
                 const u16* __restrict__ vtg,
                 float* __restrict__ lP, u16* __restrict__ aP)
{
  __shared__ u16 kl2[2 * 64 * 64];       // 16 KB
  __shared__ u16 vl2[2 * 64 * 64];       // 16 KB
  const int bx = blockIdx.x;
  const int xcd = bx & 7, b = xcd >> 1, e2 = xcd & 1;
  const int j = e2 * 264 + (bx >> 3);     // 0..527
  int M = 0;
  while (2 * (M + 1) * (M + 1) + (M + 1) <= j) ++M;   // group start = 2M^2+M
  const int ip = j - (2 * M * M + M);
  const int e = (ip >= 2 * M + 1) ? 1 : 0;
  const int s = ip - e * (2 * M + 1);
  const int pr = 2 * M + e;               // pair 0..31
  const int qa = 2 * pr, qb = 2 * pr + 1;
  const int it0 = 2 * s;
  const int it1 = min(it0 + 2, qb + 1);   // always it0+2

  const int t = threadIdx.x;
  const int w = t >> 6, l = t & 63;
  const int l15 = l & 15, lg = l >> 4;
  const int swzl = (l15 & 7) << 4;

  const int wbaseA = qa * 64 + 16 * w, wbaseB = qb * 64 + 16 * w;
  const int qrowA = wbaseA + l15, qrowB = wbaseB + l15;
  const u16* qrpA = qg + (size_t)(b * TT + qrowA) * 64;
  const u16* qrpB = qg + (size_t)(b * TT + qrowB) * 64;
  U8 qfA[2], qfB[2];
#pragma unroll
  for (int hh = 0; hh < 2; ++hh) {
    qfA[hh].q[0] = *(const uint2*)(qrpA + 32 * hh + 4 * lg);
    qfA[hh].q[1] = *(const uint2*)(qrpA + 32 * hh + 4 * lg + 16);
    qfB[hh].q[0] = *(const uint2*)(qrpB + 32 * hh + 4 * lg);
    qfB[hh].q[1] = *(const uint2*)(qrpB + 32 * hh + 4 * lg + 16);
  }

  // ---- stage both tiles (coalesced), one barrier ----
  {
    const int key = t >> 2, part = t & 3;
    const int sbase = key * 128 + part * 32;
    const int ssw = (key & 7) << 4;
    uint4 kr[2][2], vr[2][2];
#pragma unroll
    for (int tt = 0; tt < 2; ++tt) {
      int tile = it0 + tt; if (tile >= it1) tile = it1 - 1;
      const u16* ks = kg + (size_t)(b * TT + tile * 64 + key) * 64 + part * 16;
      kr[tt][0] = ((const uint4*)ks)[0];
      kr[tt][1] = ((const uint4*)ks)[1];
      const u16* vs = vtg + (size_t)(b * 64 + key) * TT + tile * 64 + part * 16;
      vr[tt][0] = ((const uint4*)vs)[0];
      vr[tt][1] = ((const uint4*)vs)[1];
    }
#pragma unroll
    for (int tt = 0; tt < 2; ++tt) {
      char* kd = (char*)kl2 + tt * 8192;
      char* vd = (char*)vl2 + tt * 8192;
      *(uint4*)(kd + ((sbase + 0) ^ ssw)) = kr[tt][0];
      *(uint4*)(kd + ((sbase + 16) ^ ssw)) = kr[tt][1];
      *(uint4*)(vd + ((sbase + 0) ^ ssw)) = vr[tt][0];
      *(uint4*)(vd + ((sbase + 16) ^ ssw)) = vr[tt][1];
    }
  }
  __syncthreads();

  const float C = 0.18033688011112042f;   // log2(e)/sqrt(64)
  float lA = 0.f, lB = 0.f;
  f32x4 accA[4], accB[4];
#pragma unroll
  for (int ct = 0; ct < 4; ++ct) {
    accA[ct] = (f32x4){0.f, 0.f, 0.f, 0.f};
    accB[ct] = (f32x4){0.f, 0.f, 0.f, 0.f};
  }

  int toff = 0;
  for (int it = it0; it < it1; ++it, toff += 8192) {
    const int kb = it * 64;
    const char* kp = (const char*)kl2 + toff;
    const char* vp = (const char*)vl2 + toff;

    // ---- QK for both chains; each kf read feeds 4 MFMAs ----
    f32x4 stA[4], stB[4];
    __builtin_amdgcn_s_setprio(1);
#pragma unroll
    for (int t4 = 0; t4 < 4; ++t4) {
      const int rbase = (16 * t4 + l15) * 128 + 8 * lg;
      U8 kf0, kf1;
      kf0.q[0] = *(const uint2*)(kp + ((rbase + 0) ^ swzl));
      kf0.q[1] = *(const uint2*)(kp + ((rbase + 32) ^ swzl));
      kf1.q[0] = *(const uint2*)(kp + ((rbase + 64) ^ swzl));
      kf1.q[1] = *(const uint2*)(kp + ((rbase + 96) ^ swzl));
      f32x4 dA = {0.f, 0.f, 0.f, 0.f};
      dA = __builtin_amdgcn_mfma_f32_16x16x32_bf16(kf0.v, qfA[0].v, dA, 0, 0, 0);
      dA = __builtin_amdgcn_mfma_f32_16x16x32_bf16(kf1.v, qfA[1].v, dA, 0, 0, 0);
      stA[t4] = dA;
      f32x4 dB = {0.f, 0.f, 0.f, 0.f};
      dB = __builtin_amdgcn_mfma_f32_16x16x32_bf16(kf0.v, qfB[0].v, dB, 0, 0, 0);
      dB = __builtin_amdgcn_mfma_f32_16x16x32_bf16(kf1.v, qfB[1].v, dB, 0, 0, 0);
      stB[t4] = dB;
    }
    __builtin_amdgcn_s_setprio(0);

    // ---- no-max softmax, both chains (independent straight-line code) ----
    float pA[16], pB[16];
    const bool maskA = (kb + 63 > wbaseA);
    if (maskA) {
#pragma unroll
      for (int t4 = 0; t4 < 4; ++t4) {
#pragma unroll
        for (int r = 0; r < 4; ++r) {
          int keyidx = kb + 16 * t4 + 4 * lg + r;
          float e1 = exp2a(stA[t4][r] * C);
          pA[t4 * 4 + r] = (keyidx > qrowA) ? 0.f : e1;
        }
      }
    } else {
#pragma unroll
      for (int t4 = 0; t4 < 4; ++t4) {
#pragma unroll
        for (int r = 0; r < 4; ++r) pA[t4 * 4 + r] = exp2a(stA[t4][r] * C);
      }
    }
    const bool maskB = (kb + 63 > wbaseB);
    if (maskB) {
#pragma unroll
      for (int t4 = 0; t4 < 4; ++t4) {
#pragma unroll
        for (int r = 0; r < 4; ++r) {
          int keyidx = kb + 16 * t4 + 4 * lg + r;
          float e1 = exp2a(stB[t4][r] * C);
          pB[t4 * 4 + r] = (keyidx > qrowB) ? 0.f : e1;
        }
      }
    } else {
#pragma unroll
      for (int t4 = 0; t4 < 4; ++t4) {
#pragma unroll
        for (int r = 0; r < 4; ++r) pB[t4 * 4 + r] = exp2a(stB[t4][r] * C);
      }
    }
    float smA[8], smB[8];
#pragma unroll
    for (int i = 0; i < 8; ++i) {
      smA[i] = pA[2 * i] + pA[2 * i + 1];
      smB[i] = pB[2 * i] + pB[2 * i + 1];
    }
#pragma unroll
    for (int i = 0; i < 4; ++i) {
      smA[i] = smA[2 * i] + smA[2 * i + 1];
      smB[i] = smB[2 * i] + smB[2 * i + 1];
    }
    float rsA = (smA[0] + smA[1]) + (smA[2] + smA[3]);
    float rsB = (smB[0] + smB[1]) + (smB[2] + smB[3]);
    rsA += __shfl_xor(rsA, 16);
    rsB += __shfl_xor(rsB, 16);
    rsA += __shfl_xor(rsA, 32);
    rsB += __shfl_xor(rsB, 32);
    lA += rsA;
    lB += rsB;

    U8 paA[2], paB[2];
#pragma unroll
    for (int u = 0; u < 2; ++u) {
#pragma unroll
      for (int k2 = 0; k2 < 4; ++k2) {
        paA[u].w[k2] = cvtpk(pA[8 * u + 2 * k2], pA[8 * u + 2 * k2 + 1]);
        paB[u].w[k2] = cvtpk(pB[8 * u + 2 * k2], pB[8 * u + 2 * k2 + 1]);
      }
    }

    // ---- PV for both chains; each vf read feeds 2 MFMAs ----
    __builtin_amdgcn_s_setprio(1);
#pragma unroll
    for (int ct = 0; ct < 4; ++ct) {
      const int vb = (16 * ct + l15) * 128 + 8 * lg;
#pragma unroll
      for (int u = 0; u < 2; ++u) {
        U8 vf;
        vf.q[0] = *(const uint2*)(vp + ((vb + 64 * u + 0) ^ swzl));
        vf.q[1] = *(const uint2*)(vp + ((vb + 64 * u + 32) ^ swzl));
        accA[ct] = __builtin_amdgcn_mfma_f32_16x16x32_bf16(paA[u].v, vf.v, accA[ct], 0, 0, 0);
        accB[ct] = __builtin_amdgcn_mfma_f32_16x16x32_bf16(paB[u].v, vf.v, accB[ct], 0, 0, 0);
      }
    }
    __builtin_amdgcn_s_setprio(0);
  }

  // ---- write partials (per-qtile compact slots) ----
  const int jqA = pr * (pr + 1) + s;
  const int jqB = pr * (pr + 1) + (pr + 1) + s;
  const size_t pbA = (size_t)(b * 1056 + jqA) * 64;
  const size_t pbB = (size_t)(b * 1056 + jqB) * 64;
  if (lg == 0) {
    lP[pbA + 16 * w + l15] = lA;
    lP[pbB + 16 * w + l15] = lB;
  }
#pragma unroll
  for (int ct = 0; ct < 4; ++ct) {
#pragma unroll
    for (int r = 0; r < 4; ++r) {
      int rin = 16 * w + 4 * lg + r;
      aP[(pbA + rin) * 64 + l15 + 16 * ct] = f2bf(accA[ct][r]);
      aP[(pbB + rin) * 64 + l15 + 16 * ct] = f2bf(accB[ct][r]);
    }
  }
}

// ---------------------------------------------------------------------------
// Kernel 2b: merge = pure sum over segments + output LayerNorm (W=2 slots).
// ---------------------------------------------------------------------------
__global__ __launch_bounds__(256)
void attn_merge2n(const float* __restrict__ lP, const u16* __restrict__ aP,
                  const float* __restrict__ go, const float* __restrict__ bgo,
                  float* __restrict__ out)
{
  const int t = threadIdx.x;
  const int w = t >> 6, c = t & 63;
  const int row = blockIdx.x * 4 + w;
  const int tid2 = row >> 6, rin = row & 63;
  const int b = tid2 >> 6, q = tid2 & 63;
  const int Q = q >> 1;
  const int base_q = b * 1056 + Q * (Q + 1) + (q & 1) * (Q + 1);
  const int ns = Q + 1;

  float L = 0.f, o = 0.f;
  for (int s = 0; s < ns; ++s) {
    const size_t pb = (size_t)(base_q + s) * 64;
    L += lP[pb + rin];
    o += bf2f(aP[(pb + rin) * 64 + c]);
  }
  o /= L;

  float s1 = o, s2 = o * o;
#pragma unroll
  for (int d = 1; d < 64; d <<= 1) {
    s1 += __shfl_xor(s1, d);
    s2 += __shfl_xor(s2, d);
  }
  float mu = s1 * (1.f / 64.f);
  float var = s2 * (1.f / 64.f) - mu * mu;
  float rs = rsqrtf(var + 1e-5f);
  out[(size_t)row * 192 + 128 + c] = (o - mu) * rs * go[c] + bgo[c];
}

// ---------------------------------------------------------------------------
// Kernel 2 last-resort fallback: single-pass LDS attn (round 2 proven).
// ---------------------------------------------------------------------------
__global__ __launch_bounds__(128)
void attn1(const u16* __restrict__ qg, const u16* __restrict__ kg,
           const u16* __restrict__ vtg,
           const float* __restrict__ go, const float* __restrict__ bgo,
           float* __restrict__ out)
{
  __shared__ u16 kl[64 * 64];
  __shared__ u16 vl[64 * 64];
  const int bx = blockIdx.x;
  const int tt = (bx < 256) ? bx : (767 - bx);
  const int b = tt >> 7;
  const int q0 = (tt & 127) * 32;
  const int tid = threadIdx.x;
  const int w = tid >> 6;
  const int l = tid & 63;
  const int l15 = l & 15;
  const int lg = l >> 4;
  const int swzl = (l15 & 7) << 4;

  const int qrow = q0 + 16 * w + l15;
  const u16* qrp = qg + (size_t)(b * TT + qrow) * 64;
  U8 qf[2];
#pragma unroll
  for (int h = 0; h < 2; ++h) {
    qf[h].q[0] = *(const uint2*)(qrp + 32 * h + 4 * lg);
    qf[h].q[1] = *(const uint2*)(qrp + 32 * h + 4 * lg + 16);
  }

  float m_run = -1e30f, l_run = 0.f;
  f32x4 acc[4];
#pragma unroll
  for (int ct = 0; ct < 4; ++ct) acc[ct] = (f32x4){0.f, 0.f, 0.f, 0.f};

  const int nkv = (q0 >> 6) + 1;
  for (int it = 0; it < nkv; ++it) {
    const int kb = it * 64;
    {
      const int key = tid >> 1;
      const int dh = (tid & 1) * 32;
      const u16* ks = kg + (size_t)(b * TT + kb + key) * 64 + dh;
      uint4 d0 = *(const uint4*)(ks + 0);
      uint4 d1 = *(const uint4*)(ks + 8);
      uint4 d2 = *(const uint4*)(ks + 16);
      uint4 d3 = *(const uint4*)(ks + 24);
      const int base = key * 128 + dh * 2;
      const int sw = (key & 7) << 4;
      char* kd = (char*)kl;
      *(uint4*)(kd + ((base + 0) ^ sw)) = d0;
      *(uint4*)(kd + ((base + 16) ^ sw)) = d1;
      *(uint4*)(kd + ((base + 32) ^ sw)) = d2;
      *(uint4*)(kd + ((base + 48) ^ sw)) = d3;
      const u16* vs = vtg + (size_t)(b * 64 + key) * TT + kb + dh;
      uint4 e0 = *(const uint4*)(vs + 0);
      uint4 e1 = *(const uint4*)(vs + 8);
      uint4 e2 = *(const uint4*)(vs + 16);
      uint4 e3 = *(const uint4*)(vs + 24);
      char* vd = (char*)vl;
      *(uint4*)(vd + ((base + 0) ^ sw)) = e0;
      *(uint4*)(vd + ((base + 16) ^ sw)) = e1;
      *(uint4*)(vd + ((base + 32) ^ sw)) = e2;
      *(uint4*)(vd + ((base + 48) ^ sw)) = e3;
    }
    __syncthreads();

    f32x4 st[4];
#pragma unroll
    for (int t4 = 0; t4 < 4; ++t4) {
      const int rbase = (16 * t4 + l15) * 128 + 8 * lg;
      const char* kp = (const char*)kl;
      U8 kf0, kf1;
      kf0.q[0] = *(const uint2*)(kp + ((rbase + 0) ^ swzl));
      kf0.q[1] = *(const uint2*)(kp + ((rbase + 32) ^ swzl));
      kf1.q[0] = *(const uint2*)(kp + ((rbase + 64) ^ swzl));
      kf1.q[1] = *(const uint2*)(kp + ((rbase + 96) ^ swzl));
      f32x4 d = {0.f, 0.f, 0.f, 0.f};
      d = __builtin_amdgcn_mfma_f32_16x16x32_bf16(kf0.v, qf[0].v, d, 0, 0, 0);
      d = __builtin_amdgcn_mfma_f32_16x16x32_bf16(kf1.v, qf[1].v, d, 0, 0, 0);
      st[t4] = d;
    }

    float sv[16];
    const bool needmask = (kb + 63 > q0 + 16 * w);
#pragma unroll
    for (int t4 = 0; t4 < 4; ++t4) {
#pragma unroll
      for (int r = 0; r < 4; ++r) {
        float sc = st[t4][r] * 0.125f;
        if (needmask) {
          int keyidx = kb + 16 * t4 + 4 * lg + r;
          if (keyidx > qrow) sc = -1e30f;
        }
        sv[t4 * 4 + r] = sc;
      }
    }
    float mt = sv[0];
#pragma unroll
    for (int i = 1; i < 16; ++i) mt = fmaxf(mt, sv[i]);
    mt = fmaxf(mt, __shfl_xor(mt, 16));
    mt = fmaxf(mt, __shfl_xor(mt, 32));
    const float mnew = fmaxf(m_run, mt);
    const float al = __expf(m_run - mnew);
    float p[16];
    float rsum = 0.f;
#pragma unroll
    for (int i = 0; i < 16; ++i) { p[i] = __expf(sv[i] - mnew); rsum += p[i]; }
    rsum += __shfl_xor(rsum, 16);
    rsum += __shfl_xor(rsum, 32);
    l_run = l_run * al + rsum;
    m_run = mnew;
    float ar[4];
#pragma unroll
    for (int r = 0; r < 4; ++r) ar[r] = __shfl(al, 4 * lg + r);
#pragma unroll
    for (int ct = 0; ct < 4; ++ct) {
#pragma unroll
      for (int r = 0; r < 4; ++r) acc[ct][r] *= ar[r];
    }
    U8 pa[2];
#pragma unroll
    for (int u = 0; u < 2; ++u) {
#pragma unroll
      for (int i = 0; i < 8; ++i) pa[u].s[i] = (short)f2bf(p[8 * u + i]);
    }

#pragma unroll
    for (int ct = 0; ct < 4; ++ct) {
      const int vb = (16 * ct + l15) * 128 + 8 * lg;
      const char* vp = (const char*)vl;
#pragma unroll
      for (int u = 0; u < 2; ++u) {
        U8 vf;
        vf.q[0] = *(const uint2*)(vp + ((vb + 64 * u + 0) ^ swzl));
        vf.q[1] = *(const uint2*)(vp + ((vb + 64 * u + 32) ^ swzl));
        acc[ct] = __builtin_amdgcn_mfma_f32_16x16x32_bf16(pa[u].v, vf.v, acc[ct], 0, 0, 0);
      }
    }
    __syncthreads();
  }

  float linv[4];
#pragma unroll
  for (int r = 0; r < 4; ++r) linv[r] = 1.f / __shfl(l_run, 4 * lg + r);
  float o[4][4];
#pragma unroll
  for (int ct = 0; ct < 4; ++ct) {
#pragma unroll
    for (int r = 0; r < 4; ++r) o[ct][r] = acc[ct][r] * linv[r];
  }
  float s1[4], s2[4];
#pragma unroll
  for (int r = 0; r < 4; ++r) {
    s1[r] = o[0][r] + o[1][r] + o[2][r] + o[3][r];
    s2[r] = o[0][r] * o[0][r] + o[1][r] * o[1][r] + o[2][r] * o[2][r] + o[3][r] * o[3][r];
#pragma unroll
    for (int d = 1; d < 16; d <<= 1) {
      s1[r] += __shfl_xor(s1[r], d);
      s2[r] += __shfl_xor(s2[r], d);
    }
  }
  float gov[4], bgv2[4];
#pragma unroll
  for (int ct = 0; ct < 4; ++ct) {
    gov[ct] = go[16 * ct + l15];
    bgv2[ct] = bgo[16 * ct + l15];
  }
#pragma unroll
  for (int r = 0; r < 4; ++r) {
    float mu = s1[r] * (1.f / 64.f);
    float var = s2[r] * (1.f / 64.f) - mu * mu;
    float rs = rsqrtf(var + 1e-5f);
    int row = q0 + 16 * w + 4 * lg + r;
    float* op = out + (size_t)(b * TT + row) * 192 + 128;
#pragma unroll
    for (int ct = 0; ct < 4; ++ct)
      op[16 * ct + l15] = (o[ct][r] - mu) * rs * gov[ct] + bgv2[ct];
  }
}

extern "C" void kernel_launch(void* const* d_in, const int* in_sizes, int n_in,
                              void* d_out, int out_size, void* d_ws, size_t ws_size,
                              hipStream_t stream) {
  (void)in_sizes; (void)n_in; (void)out_size;
  const float* x   = (const float*)d_in[0];
  const float* Wq  = (const float*)d_in[1];
  const float* bq  = (const float*)d_in[2];
  const float* Wk  = (const float*)d_in[3];
  const float* bk  = (const float*)d_in[4];
  const float* Wv  = (const float*)d_in[5];
  const float* bv  = (const float*)d_in[6];
  const float* gq  = (const float*)d_in[7];
  const float* bgq = (const float*)d_in[8];
  const float* gk  = (const float*)d_in[9];
  const float* bgk = (const float*)d_in[10];
  const float* gv  = (const float*)d_in[11];
  const float* bgv = (const float*)d_in[12];
  const float* go  = (const float*)d_in[13];
  const float* bgo = (const float*)d_in[14];
  float* out = (float*)d_out;

  char* wsb = (char*)d_ws;
  u16* qws  = (u16*)wsb;
  u16* kws  = (u16*)(wsb + (2u << 20));
  u16* vtws = (u16*)(wsb + (4u << 20));
  u16* wfr  = (u16*)(wsb + (6u << 20));
  const size_t OFF_LP = (6u << 20) + 65536;

  wpack<<<48, 64, 0, stream>>>(Wq, Wk, Wv, wfr);
  proj_mfma<<<768, 256, 0, stream>>>(x, wfr, bq, bk, bv,
                                     gq, bgq, gk, bgk, gv, bgv,
                                     qws, kws, vtws, out);

  {
    // W=2 paired: 4 batches x 1056 qtile-segment slots; l (f32) + acc (bf16)
    const size_t SEG2 = 4u * 1056;
    const size_t LPS = SEG2 * 64 * 4;               // 1,081,344
    const size_t APS = SEG2 * 64 * 64 * 2;          // 34,603,008
    const size_t OFF_AP = OFF_LP + LPS;
    const size_t NEED = OFF_AP + APS;               // ~42 MB
    // W=4 pair fallback sizes (round-12 proven) not needed: NEED < 256MB ws.

    if (ws_size >= NEED) {
      float* lP = (float*)(wsb + OFF_LP);
      u16*   aP = (u16*)(wsb + OFF_AP);
      attn_pair2n<<<2112, 256, 0, stream>>>(qws, kws, vtws, lP, aP);
      attn_merge2n<<<4096, 256, 0, stream>>>(lP, aP, go, bgo, out);
    } else {
      attn1<<<512, 128, 0, stream>>>(qws, kws, vtws, go, bgo, out);
    }
  }
}

// Round 18
// 59.078 us; speedup vs baseline: 1.1662x; 1.1484x over previous
//
#include <hip/hip_runtime.h>

#define TT 4096

typedef unsigned short u16;
typedef unsigned int u32;

typedef short bf16x8 __attribute__((ext_vector_type(8)));
typedef float f32x4 __attribute__((ext_vector_type(4)));

union U8 {
  uint2 q[2];
  uint4 u4;
  bf16x8 v;
  short s[8];
  u32 w[4];
};

static __device__ __forceinline__ u16 f2bf(float f) {
  union { float f; u32 u; } cv;
  cv.f = f;
  u32 r = cv.u + 0x7FFFu + ((cv.u >> 16) & 1u);
  return (u16)(r >> 16);
}
static __device__ __forceinline__ u32 pk2(float a, float b) {
  return (u32)f2bf(a) | ((u32)f2bf(b) << 16);
}
static __device__ __forceinline__ float bf2f(u16 h) {
  union { u32 u; float f; } cv;
  cv.u = ((u32)h) << 16;
  return cv.f;
}
static __device__ __forceinline__ float exp2a(float x) {
  float r; asm("v_exp_f32 %0, %1" : "=v"(r) : "v"(x)); return r;
}
static __device__ __forceinline__ u32 cvtpk(float lo, float hi) {
  u32 r; asm("v_cvt_pk_bf16_f32 %0, %1, %2" : "=v"(r) : "v"(lo), "v"(hi)); return r;
}

// ---------------------------------------------------------------------------
// Kernel 0: pack W{q,k,v} into MFMA B-fragment layout, bf16.
// ---------------------------------------------------------------------------
__global__ __launch_bounds__(64)
void wpack(const float* __restrict__ Wq, const float* __restrict__ Wk,
           const float* __restrict__ Wv, u16* __restrict__ wf)
{
  const int g = blockIdx.x;              // 0..47
  const int p = g >> 4, s = (g >> 2) & 3, nt = g & 3;
  const int l = threadIdx.x, lg = l >> 4, l15 = l & 15;
  const float* W = (p == 0) ? Wq : (p == 1) ? Wk : Wv;
  const int n = l15 + 16 * nt;
  U8 o;
#pragma unroll
  for (int j = 0; j < 8; ++j) {
    int k = 32 * s + ((j < 4) ? (4 * lg + j) : (16 + 4 * lg + (j - 4)));
    o.s[j] = (short)f2bf(W[k * 64 + n]);
  }
  *(uint4*)(wf + (size_t)(g * 64 + l) * 8) = o.u4;
}

// ---------------------------------------------------------------------------
// Kernel 1: projections via MFMA + LayerNorm. 768 blocks x 256 thr (4 waves).
// v output transposed via LDS then coalesced b128 stores.
// ---------------------------------------------------------------------------
__global__ __launch_bounds__(256)
void proj_mfma(const float* __restrict__ x, const u16* __restrict__ wf,
               const float* __restrict__ bq, const float* __restrict__ bk,
               const float* __restrict__ bv,
               const float* __restrict__ gq, const float* __restrict__ bgq,
               const float* __restrict__ gk, const float* __restrict__ bgk,
               const float* __restrict__ gv, const float* __restrict__ bgv,
               u16* __restrict__ qo, u16* __restrict__ ko, u16* __restrict__ vto,
               float* __restrict__ out)
{
  __shared__ u16 xs[64 * 130];           // 16.25 KB; staging + v-transpose
  const int bx = blockIdx.x;
  const int xcd = bx & 7, i = bx >> 3;
  const int tile = xcd * 32 + (i & 31);  // 0..255
  const int p = i >> 5;                  // 0..2
  const int rowbase = tile * 64;
  const int t = threadIdx.x;

  {
    const int row = t >> 2, seg = t & 3;
    const float4* src = (const float4*)(x + (size_t)(rowbase + row) * 128 + seg * 32);
    float4 f[8];
#pragma unroll
    for (int q = 0; q < 8; ++q) f[q] = src[q];
    if ((p == 0 && seg < 2) || (p == 1 && seg >= 2)) {
      float4* dst = (float4*)(out + (size_t)(rowbase + row) * 192 + seg * 32);
#pragma unroll
      for (int q = 0; q < 8; ++q) dst[q] = f[q];
    }
    const int base = row * 256 + seg * 64;
    const int swz = (row & 7) << 4;
    char* xb = (char*)xs;
#pragma unroll
    for (int q = 0; q < 4; ++q) {
      uint4 u;
      u.x = pk2(f[2 * q].x, f[2 * q].y);
      u.y = pk2(f[2 * q].z, f[2 * q].w);
      u.z = pk2(f[2 * q + 1].x, f[2 * q + 1].y);
      u.w = pk2(f[2 * q + 1].z, f[2 * q + 1].w);
      *(uint4*)(xb + ((base + 16 * q) ^ swz)) = u;
    }
  }

  const int w = t >> 6, l = t & 63, lg = l >> 4, l15 = l & 15;
  U8 bfr[4][4];
  const u16* wp = wf + (size_t)p * (16 * 64 * 8);
#pragma unroll
  for (int s = 0; s < 4; ++s)
#pragma unroll
    for (int nt = 0; nt < 4; ++nt)
      bfr[s][nt].u4 = *(const uint4*)(wp + ((s * 4 + nt) * 64 + l) * 8);

  __syncthreads();

  f32x4 acc[4];
#pragma unroll
  for (int nt = 0; nt < 4; ++nt) acc[nt] = (f32x4){0.f, 0.f, 0.f, 0.f};
  const int abase = (16 * w + l15) * 256;
  const int aswz = (l15 & 7) << 4;
  const char* xb = (const char*)xs;
#pragma unroll
  for (int s = 0; s < 4; ++s) {
    U8 af;
    af.q[0] = *(const uint2*)(xb + ((abase + s * 64 + 8 * lg) ^ aswz));
    af.q[1] = *(const uint2*)(xb + ((abase + s * 64 + 8 * lg + 32) ^ aswz));
#pragma unroll
    for (int nt = 0; nt < 4; ++nt)
      acc[nt] = __builtin_amdgcn_mfma_f32_16x16x32_bf16(af.v, bfr[s][nt].v, acc[nt], 0, 0, 0);
  }

  const float* bb = (p == 0) ? bq : (p == 1) ? bk : bv;
  const float* gg = (p == 0) ? gq : (p == 1) ? gk : gv;
  const float* hh = (p == 0) ? bgq : (p == 1) ? bgk : bgv;
  float bcol[4], gcol[4], hcol[4];
#pragma unroll
  for (int nt = 0; nt < 4; ++nt) {
    int col = l15 + 16 * nt;
    bcol[nt] = bb[col]; gcol[nt] = gg[col]; hcol[nt] = hh[col];
  }
  float vals[4][4];
#pragma unroll
  for (int nt = 0; nt < 4; ++nt)
#pragma unroll
    for (int r = 0; r < 4; ++r) vals[nt][r] = acc[nt][r] + bcol[nt];

  float s1[4], s2[4];
#pragma unroll
  for (int r = 0; r < 4; ++r) {
    s1[r] = vals[0][r] + vals[1][r] + vals[2][r] + vals[3][r];
    s2[r] = vals[0][r] * vals[0][r] + vals[1][r] * vals[1][r]
          + vals[2][r] * vals[2][r] + vals[3][r] * vals[3][r];
#pragma unroll
    for (int d = 1; d < 16; d <<= 1) {
      s1[r] += __shfl_xor(s1[r], d);
      s2[r] += __shfl_xor(s2[r], d);
    }
  }

  if (p < 2) {
    u16* dst = (p == 0) ? qo : ko;
#pragma unroll
    for (int r = 0; r < 4; ++r) {
      float mu = s1[r] * (1.f / 64.f);
      float var = s2[r] * (1.f / 64.f) - mu * mu;
      float rs = rsqrtf(var + 1e-5f);
      int grow = rowbase + 16 * w + 4 * lg + r;
#pragma unroll
      for (int nt = 0; nt < 4; ++nt)
        dst[(size_t)grow * 64 + l15 + 16 * nt] =
            f2bf((vals[nt][r] - mu) * rs * gcol[nt] + hcol[nt]);
    }
  } else {
    // v: LDS transpose (stride-65 pad) then coalesced stores
    u16* vls = xs;
    __syncthreads();                      // all A-frag reads done
#pragma unroll
    for (int r = 0; r < 4; ++r) {
      float mu = s1[r] * (1.f / 64.f);
      float var = s2[r] * (1.f / 64.f) - mu * mu;
      float rs = rsqrtf(var + 1e-5f);
      int row = 16 * w + 4 * lg + r;
#pragma unroll
      for (int nt = 0; nt < 4; ++nt)
        vls[row * 65 + l15 + 16 * nt] =
            f2bf((vals[nt][r] - mu) * rs * gcol[nt] + hcol[nt]);
    }
    __syncthreads();
    const int b = rowbase >> 12;
    const int tl = rowbase & 4095;
    const int col = t >> 2;               // 0..63
    const int tq = (t & 3) * 16;          // row offset 0,16,32,48
    U8 o0, o1;
#pragma unroll
    for (int i = 0; i < 8; ++i) o0.s[i] = (short)vls[(tq + i) * 65 + col];
#pragma unroll
    for (int i = 0; i < 8; ++i) o1.s[i] = (short)vls[(tq + 8 + i) * 65 + col];
    u16* dst = vto + (size_t)(b * 64 + col) * TT + tl + tq;
    *(uint4*)(dst + 0) = o0.u4;
    *(uint4*)(dst + 8) = o1.u4;
  }
}

// ---------------------------------------------------------------------------
// Kernel 2a: paired-qtile W=4 segment, NO-MAX softmax, branch-free chains.
// Pair {qa=2pr, qb=2pr+1} shares every kf/vf LDS read. One barrier per block.
// Partials: l (f32) + unnormalized acc (bf16); merge is a pure sum.
// PROVEN BEST: round-12/15 config, 58.9 us total.
// ---------------------------------------------------------------------------
__global__ __launch_bounds__(256)
void attn_pair4n(const u16* __restrict__ qg, const u16* __restrict__ kg,
                 const u16* __restrict__ vtg,
                 float* __restrict__ lP, u16* __restrict__ aP)
{
  __shared__ u16 kl4[4 * 64 * 64];
  __shared__ u16 vl4[4 * 64 * 64];
  const int bx = blockIdx.x;
  const int xcd = bx & 7, b = xcd >> 1, e2 = xcd & 1;
  const int j = e2 * 136 + (bx >> 3);     // 0..271
  int M = 0;
  while ((M + 1) * (M + 2) <= j) ++M;     // group M = pairs {2M, 2M+1}
  const int ip = j - M * (M + 1);
  const int e = (ip >= M + 1) ? 1 : 0;
  const int s = ip - e * (M + 1);
  const int pr = 2 * M + e;               // pair 0..31
  const int qa = 2 * pr, qb = 2 * pr + 1;
  const int it0 = 4 * s;
  const int it1 = min(it0 + 4, qb + 1);

  const int t = threadIdx.x;
  const int w = t >> 6, l = t & 63;
  const int l15 = l & 15, lg = l >> 4;
  const int swzl = (l15 & 7) << 4;

  const int wbaseA = qa * 64 + 16 * w, wbaseB = qb * 64 + 16 * w;
  const int qrowA = wbaseA + l15, qrowB = wbaseB + l15;
  const u16* qrpA = qg + (size_t)(b * TT + qrowA) * 64;
  const u16* qrpB = qg + (size_t)(b * TT + qrowB) * 64;
  U8 qfA[2], qfB[2];
#pragma unroll
  for (int hh = 0; hh < 2; ++hh) {
    qfA[hh].q[0] = *(const uint2*)(qrpA + 32 * hh + 4 * lg);
    qfA[hh].q[1] = *(const uint2*)(qrpA + 32 * hh + 4 * lg + 16);
    qfB[hh].q[0] = *(const uint2*)(qrpB + 32 * hh + 4 * lg);
    qfB[hh].q[1] = *(const uint2*)(qrpB + 32 * hh + 4 * lg + 16);
  }

  // ---- stage the whole segment (coalesced), one barrier ----
  {
    const int key = t >> 2, part = t & 3;
    const int sbase = key * 128 + part * 32;
    const int ssw = (key & 7) << 4;
    uint4 kr[4][2], vr[4][2];
#pragma unroll
    for (int tt = 0; tt < 4; ++tt) {
      int tile = it0 + tt; if (tile >= it1) tile = it1 - 1;
      const u16* ks = kg + (size_t)(b * TT + tile * 64 + key) * 64 + part * 16;
      kr[tt][0] = ((const uint4*)ks)[0];
      kr[tt][1] = ((const uint4*)ks)[1];
      const u16* vs = vtg + (size_t)(b * 64 + key) * TT + tile * 64 + part * 16;
      vr[tt][0] = ((const uint4*)vs)[0];
      vr[tt][1] = ((const uint4*)vs)[1];
    }
#pragma unroll
    for (int tt = 0; tt < 4; ++tt) {
      char* kd = (char*)kl4 + tt * 8192;
      char* vd = (char*)vl4 + tt * 8192;
      *(uint4*)(kd + ((sbase + 0) ^ ssw)) = kr[tt][0];
      *(uint4*)(kd + ((sbase + 16) ^ ssw)) = kr[tt][1];
      *(uint4*)(vd + ((sbase + 0) ^ ssw)) = vr[tt][0];
      *(uint4*)(vd + ((sbase + 16) ^ ssw)) = vr[tt][1];
    }
  }
  __syncthreads();

  const float C = 0.18033688011112042f;   // log2(e)/sqrt(64)
  float lA = 0.f, lB = 0.f;
  f32x4 accA[4], accB[4];
#pragma unroll
  for (int ct = 0; ct < 4; ++ct) {
    accA[ct] = (f32x4){0.f, 0.f, 0.f, 0.f};
    accB[ct] = (f32x4){0.f, 0.f, 0.f, 0.f};
  }

  int toff = 0;
  for (int it = it0; it < it1; ++it, toff += 8192) {
    const int kb = it * 64;
    const char* kp = (const char*)kl4 + toff;
    const char* vp = (const char*)vl4 + toff;

    // ---- QK for both chains; each kf read feeds 4 MFMAs ----
    f32x4 stA[4], stB[4];
    __builtin_amdgcn_s_setprio(1);
#pragma unroll
    for (int t4 = 0; t4 < 4; ++t4) {
      const int rbase = (16 * t4 + l15) * 128 + 8 * lg;
      U8 kf0, kf1;
      kf0.q[0] = *(const uint2*)(kp + ((rbase + 0) ^ swzl));
      kf0.q[1] = *(const uint2*)(kp + ((rbase + 32) ^ swzl));
      kf1.q[0] = *(const uint2*)(kp + ((rbase + 64) ^ swzl));
      kf1.q[1] = *(const uint2*)(kp + ((rbase + 96) ^ swzl));
      f32x4 dA = {0.f, 0.f, 0.f, 0.f};
      dA = __builtin_amdgcn_mfma_f32_16x16x32_bf16(kf0.v, qfA[0].v, dA, 0, 0, 0);
      dA = __builtin_amdgcn_mfma_f32_16x16x32_bf16(kf1.v, qfA[1].v, dA, 0, 0, 0);
      stA[t4] = dA;
      f32x4 dB = {0.f, 0.f, 0.f, 0.f};
      dB = __builtin_amdgcn_mfma_f32_16x16x32_bf16(kf0.v, qfB[0].v, dB, 0, 0, 0);
      dB = __builtin_amdgcn_mfma_f32_16x16x32_bf16(kf1.v, qfB[1].v, dB, 0, 0, 0);
      stB[t4] = dB;
    }
    __builtin_amdgcn_s_setprio(0);

    // ---- no-max softmax, both chains (independent straight-line code) ----
    float pA[16], pB[16];
    const bool maskA = (kb + 63 > wbaseA);
    if (maskA) {
#pragma unroll
      for (int t4 = 0; t4 < 4; ++t4) {
#pragma unroll
        for (int r = 0; r < 4; ++r) {
          int keyidx = kb + 16 * t4 + 4 * lg + r;
          float e1 = exp2a(stA[t4][r] * C);
          pA[t4 * 4 + r] = (keyidx > qrowA) ? 0.f : e1;
        }
      }
    } else {
#pragma unroll
      for (int t4 = 0; t4 < 4; ++t4) {
#pragma unroll
        for (int r = 0; r < 4; ++r) pA[t4 * 4 + r] = exp2a(stA[t4][r] * C);
      }
    }
    const bool maskB = (kb + 63 > wbaseB);
    if (maskB) {
#pragma unroll
      for (int t4 = 0; t4 < 4; ++t4) {
#pragma unroll
        for (int r = 0; r < 4; ++r) {
          int keyidx = kb + 16 * t4 + 4 * lg + r;
          float e1 = exp2a(stB[t4][r] * C);
          pB[t4 * 4 + r] = (keyidx > qrowB) ? 0.f : e1;
        }
      }
    } else {
#pragma unroll
      for (int t4 = 0; t4 < 4; ++t4) {
#pragma unroll
        for (int r = 0; r < 4; ++r) pB[t4 * 4 + r] = exp2a(stB[t4][r] * C);
      }
    }
    float smA[8], smB[8];
#pragma unroll
    for (int i = 0; i < 8; ++i) {
      smA[i] = pA[2 * i] + pA[2 * i + 1];
      smB[i] = pB[2 * i] + pB[2 * i + 1];
    }
#pragma unroll
    for (int i = 0; i < 4; ++i) {
      smA[i] = smA[2 * i] + smA[2 * i + 1];
      smB[i] = smB[2 * i] + smB[2 * i + 1];
    }
    float rsA = (smA[0] + smA[1]) + (smA[2] + smA[3]);
    float rsB = (smB[0] + smB[1]) + (smB[2] + smB[3]);
    rsA += __shfl_xor(rsA, 16);
    rsB += __shfl_xor(rsB, 16);
    rsA += __shfl_xor(rsA, 32);
    rsB += __shfl_xor(rsB, 32);
    lA += rsA;
    lB += rsB;

    U8 paA[2], paB[2];
#pragma unroll
    for (int u = 0; u < 2; ++u) {
#pragma unroll
      for (int k2 = 0; k2 < 4; ++k2) {
        paA[u].w[k2] = cvtpk(pA[8 * u + 2 * k2], pA[8 * u + 2 * k2 + 1]);
        paB[u].w[k2] = cvtpk(pB[8 * u + 2 * k2], pB[8 * u + 2 * k2 + 1]);
      }
    }

    // ---- PV for both chains; each vf read feeds 2 MFMAs ----
    __builtin_amdgcn_s_setprio(1);
#pragma unroll
    for (int ct = 0; ct < 4; ++ct) {
      const int vb = (16 * ct + l15) * 128 + 8 * lg;
#pragma unroll
      for (int u = 0; u < 2; ++u) {
        U8 vf;
        vf.q[0] = *(const uint2*)(vp + ((vb + 64 * u + 0) ^ swzl));
        vf.q[1] = *(const uint2*)(vp + ((vb + 64 * u + 32) ^ swzl));
        accA[ct] = __builtin_amdgcn_mfma_f32_16x16x32_bf16(paA[u].v, vf.v, accA[ct], 0, 0, 0);
        accB[ct] = __builtin_amdgcn_mfma_f32_16x16x32_bf16(paB[u].v, vf.v, accB[ct], 0, 0, 0);
      }
    }
    __builtin_amdgcn_s_setprio(0);
  }

  // ---- write partials (per-qtile compact slots; merge4n-compatible) ----
  const int jqA = 2 * M * (M + 1) + (2 * e) * (M + 1) + s;
  const int jqB = 2 * M * (M + 1) + (2 * e + 1) * (M + 1) + s;
  const size_t pbA = (size_t)(b * 544 + jqA) * 64;
  const size_t pbB = (size_t)(b * 544 + jqB) * 64;
  if (lg == 0) {
    lP[pbA + 16 * w + l15] = lA;
    lP[pbB + 16 * w + l15] = lB;
  }
#pragma unroll
  for (int ct = 0; ct < 4; ++ct) {
#pragma unroll
    for (int r = 0; r < 4; ++r) {
      int rin = 16 * w + 4 * lg + r;
      aP[(pbA + rin) * 64 + l15 + 16 * ct] = f2bf(accA[ct][r]);
      aP[(pbB + rin) * 64 + l15 + 16 * ct] = f2bf(accB[ct][r]);
    }
  }
}

// ---------------------------------------------------------------------------
// Kernel 2b: merge = pure sum over segments + output LayerNorm.
// ---------------------------------------------------------------------------
__global__ __launch_bounds__(256)
void attn_merge4n(const float* __restrict__ lP, const u16* __restrict__ aP,
                  const float* __restrict__ go, const float* __restrict__ bgo,
                  float* __restrict__ out)
{
  const int t = threadIdx.x;
  const int w = t >> 6, c = t & 63;
  const int row = blockIdx.x * 4 + w;
  const int tid2 = row >> 6, rin = row & 63;
  const int b = tid2 >> 6, q = tid2 & 63;
  const int Q = q >> 2;
  const int base_q = b * 544 + 2 * Q * (Q + 1) + (q & 3) * (Q + 1);
  const int ns = Q + 1;

  float L = 0.f, o = 0.f;
  for (int s = 0; s < ns; ++s) {
    const size_t pb = (size_t)(base_q + s) * 64;
    L += lP[pb + rin];
    o += bf2f(aP[(pb + rin) * 64 + c]);
  }
  o /= L;

  float s1 = o, s2 = o * o;
#pragma unroll
  for (int d = 1; d < 64; d <<= 1) {
    s1 += __shfl_xor(s1, d);
    s2 += __shfl_xor(s2, d);
  }
  float mu = s1 * (1.f / 64.f);
  float var = s2 * (1.f / 64.f) - mu * mu;
  float rs = rsqrtf(var + 1e-5f);
  out[(size_t)row * 192 + 128 + c] = (o - mu) * rs * go[c] + bgo[c];
}

// ---------------------------------------------------------------------------
// Kernel 2 last-resort fallback: single-pass LDS attn (round 2 proven).
// ---------------------------------------------------------------------------
__global__ __launch_bounds__(128)
void attn1(const u16* __restrict__ qg, const u16* __restrict__ kg,
           const u16* __restrict__ vtg,
           const float* __restrict__ go, const float* __restrict__ bgo,
           float* __restrict__ out)
{
  __shared__ u16 kl[64 * 64];
  __shared__ u16 vl[64 * 64];
  const int bx = blockIdx.x;
  const int tt = (bx < 256) ? bx : (767 - bx);
  const int b = tt >> 7;
  const int q0 = (tt & 127) * 32;
  const int tid = threadIdx.x;
  const int w = tid >> 6;
  const int l = tid & 63;
  const int l15 = l & 15;
  const int lg = l >> 4;
  const int swzl = (l15 & 7) << 4;

  const int qrow = q0 + 16 * w + l15;
  const u16* qrp = qg + (size_t)(b * TT + qrow) * 64;
  U8 qf[2];
#pragma unroll
  for (int h = 0; h < 2; ++h) {
    qf[h].q[0] = *(const uint2*)(qrp + 32 * h + 4 * lg);
    qf[h].q[1] = *(const uint2*)(qrp + 32 * h + 4 * lg + 16);
  }

  float m_run = -1e30f, l_run = 0.f;
  f32x4 acc[4];
#pragma unroll
  for (int ct = 0; ct < 4; ++ct) acc[ct] = (f32x4){0.f, 0.f, 0.f, 0.f};

  const int nkv = (q0 >> 6) + 1;
  for (int it = 0; it < nkv; ++it) {
    const int kb = it * 64;
    {
      const int key = tid >> 1;
      const int dh = (tid & 1) * 32;
      const u16* ks = kg + (size_t)(b * TT + kb + key) * 64 + dh;
      uint4 d0 = *(const uint4*)(ks + 0);
      uint4 d1 = *(const uint4*)(ks + 8);
      uint4 d2 = *(const uint4*)(ks + 16);
      uint4 d3 = *(const uint4*)(ks + 24);
      const int base = key * 128 + dh * 2;
      const int sw = (key & 7) << 4;
      char* kd = (char*)kl;
      *(uint4*)(kd + ((base + 0) ^ sw)) = d0;
      *(uint4*)(kd + ((base + 16) ^ sw)) = d1;
      *(uint4*)(kd + ((base + 32) ^ sw)) = d2;
      *(uint4*)(kd + ((base + 48) ^ sw)) = d3;
      const u16* vs = vtg + (size_t)(b * 64 + key) * TT + kb + dh;
      uint4 e0 = *(const uint4*)(vs + 0);
      uint4 e1 = *(const uint4*)(vs + 8);
      uint4 e2 = *(const uint4*)(vs + 16);
      uint4 e3 = *(const uint4*)(vs + 24);
      char* vd = (char*)vl;
      *(uint4*)(vd + ((base + 0) ^ sw)) = e0;
      *(uint4*)(vd + ((base + 16) ^ sw)) = e1;
      *(uint4*)(vd + ((base + 32) ^ sw)) = e2;
      *(uint4*)(vd + ((base + 48) ^ sw)) = e3;
    }
    __syncthreads();

    f32x4 st[4];
#pragma unroll
    for (int t4 = 0; t4 < 4; ++t4) {
      const int rbase = (16 * t4 + l15) * 128 + 8 * lg;
      const char* kp = (const char*)kl;
      U8 kf0, kf1;
      kf0.q[0] = *(const uint2*)(kp + ((rbase + 0) ^ swzl));
      kf0.q[1] = *(const uint2*)(kp + ((rbase + 32) ^ swzl));
      kf1.q[0] = *(const uint2*)(kp + ((rbase + 64) ^ swzl));
      kf1.q[1] = *(const uint2*)(kp + ((rbase + 96) ^ swzl));
      f32x4 d = {0.f, 0.f, 0.f, 0.f};
      d = __builtin_amdgcn_mfma_f32_16x16x32_bf16(kf0.v, qf[0].v, d, 0, 0, 0);
      d = __builtin_amdgcn_mfma_f32_16x16x32_bf16(kf1.v, qf[1].v, d, 0, 0, 0);
      st[t4] = d;
    }

    float sv[16];
    const bool needmask = (kb + 63 > q0 + 16 * w);
#pragma unroll
    for (int t4 = 0; t4 < 4; ++t4) {
#pragma unroll
      for (int r = 0; r < 4; ++r) {
        float sc = st[t4][r] * 0.125f;
        if (needmask) {
          int keyidx = kb + 16 * t4 + 4 * lg + r;
          if (keyidx > qrow) sc = -1e30f;
        }
        sv[t4 * 4 + r] = sc;
      }
    }
    float mt = sv[0];
#pragma unroll
    for (int i = 1; i < 16; ++i) mt = fmaxf(mt, sv[i]);
    mt = fmaxf(mt, __shfl_xor(mt, 16));
    mt = fmaxf(mt, __shfl_xor(mt, 32));
    const float mnew = fmaxf(m_run, mt);
    const float al = __expf(m_run - mnew);
    float p[16];
    float rsum = 0.f;
#pragma unroll
    for (int i = 0; i < 16; ++i) { p[i] = __expf(sv[i] - mnew); rsum += p[i]; }
    rsum += __shfl_xor(rsum, 16);
    rsum += __shfl_xor(rsum, 32);
    l_run = l_run * al + rsum;
    m_run = mnew;
    float ar[4];
#pragma unroll
    for (int r = 0; r < 4; ++r) ar[r] = __shfl(al, 4 * lg + r);
#pragma unroll
    for (int ct = 0; ct < 4; ++ct) {
#pragma unroll
      for (int r = 0; r < 4; ++r) acc[ct][r] *= ar[r];
    }
    U8 pa[2];
#pragma unroll
    for (int u = 0; u < 2; ++u) {
#pragma unroll
      for (int i = 0; i < 8; ++i) pa[u].s[i] = (short)f2bf(p[8 * u + i]);
    }

#pragma unroll
    for (int ct = 0; ct < 4; ++ct) {
      const int vb = (16 * ct + l15) * 128 + 8 * lg;
      const char* vp = (const char*)vl;
#pragma unroll
      for (int u = 0; u < 2; ++u) {
        U8 vf;
        vf.q[0] = *(const uint2*)(vp + ((vb + 64 * u + 0) ^ swzl));
        vf.q[1] = *(const uint2*)(vp + ((vb + 64 * u + 32) ^ swzl));
        acc[ct] = __builtin_amdgcn_mfma_f32_16x16x32_bf16(pa[u].v, vf.v, acc[ct], 0, 0, 0);
      }
    }
    __syncthreads();
  }

  float linv[4];
#pragma unroll
  for (int r = 0; r < 4; ++r) linv[r] = 1.f / __shfl(l_run, 4 * lg + r);
  float o[4][4];
#pragma unroll
  for (int ct = 0; ct < 4; ++ct) {
#pragma unroll
    for (int r = 0; r < 4; ++r) o[ct][r] = acc[ct][r] * linv[r];
  }
  float s1[4], s2[4];
#pragma unroll
  for (int r = 0; r < 4; ++r) {
    s1[r] = o[0][r] + o[1][r] + o[2][r] + o[3][r];
    s2[r] = o[0][r] * o[0][r] + o[1][r] * o[1][r] + o[2][r] * o[2][r] + o[3][r] * o[3][r];
#pragma unroll
    for (int d = 1; d < 16; d <<= 1) {
      s1[r] += __shfl_xor(s1[r], d);
      s2[r] += __shfl_xor(s2[r], d);
    }
  }
  float gov[4], bgv2[4];
#pragma unroll
  for (int ct = 0; ct < 4; ++ct) {
    gov[ct] = go[16 * ct + l15];
    bgv2[ct] = bgo[16 * ct + l15];
  }
#pragma unroll
  for (int r = 0; r < 4; ++r) {
    float mu = s1[r] * (1.f / 64.f);
    float var = s2[r] * (1.f / 64.f) - mu * mu;
    float rs = rsqrtf(var + 1e-5f);
    int row = q0 + 16 * w + 4 * lg + r;
    float* op = out + (size_t)(b * TT + row) * 192 + 128;
#pragma unroll
    for (int ct = 0; ct < 4; ++ct)
      op[16 * ct + l15] = (o[ct][r] - mu) * rs * gov[ct] + bgv2[ct];
  }
}

extern "C" void kernel_launch(void* const* d_in, const int* in_sizes, int n_in,
                              void* d_out, int out_size, void* d_ws, size_t ws_size,
                              hipStream_t stream) {
  (void)in_sizes; (void)n_in; (void)out_size;
  const float* x   = (const float*)d_in[0];
  const float* Wq  = (const float*)d_in[1];
  const float* bq  = (const float*)d_in[2];
  const float* Wk  = (const float*)d_in[3];
  const float* bk  = (const float*)d_in[4];
  const float* Wv  = (const float*)d_in[5];
  const float* bv  = (const float*)d_in[6];
  const float* gq  = (const float*)d_in[7];
  const float* bgq = (const float*)d_in[8];
  const float* gk  = (const float*)d_in[9];
  const float* bgk = (const float*)d_in[10];
  const float* gv  = (const float*)d_in[11];
  const float* bgv = (const float*)d_in[12];
  const float* go  = (const float*)d_in[13];
  const float* bgo = (const float*)d_in[14];
  float* out = (float*)d_out;

  char* wsb = (char*)d_ws;
  u16* qws  = (u16*)wsb;
  u16* kws  = (u16*)(wsb + (2u << 20));
  u16* vtws = (u16*)(wsb + (4u << 20));
  u16* wfr  = (u16*)(wsb + (6u << 20));
  const size_t OFF_LP = (6u << 20) + 65536;

  wpack<<<48, 64, 0, stream>>>(Wq, Wk, Wv, wfr);
  proj_mfma<<<768, 256, 0, stream>>>(x, wfr, bq, bk, bv,
                                     gq, bgq, gk, bgk, gv, bgv,
                                     qws, kws, vtws, out);

  {
    // W=4 paired: 4 batches x 544 qtile-segment slots; l (f32) + acc (bf16)
    const size_t SEG4 = 4u * 544;
    const size_t LPS = SEG4 * 64 * 4;               // 557,056
    const size_t APS = SEG4 * 64 * 64 * 2;          // 17,825,792
    const size_t OFF_AP = OFF_LP + LPS;
    const size_t NEED = OFF_AP + APS;               // ~24.7 MB

    if (ws_size >= NEED) {
      float* lP = (float*)(wsb + OFF_LP);
      u16*   aP = (u16*)(wsb + OFF_AP);
      attn_pair4n<<<1088, 256, 0, stream>>>(qws, kws, vtws, lP, aP);
      attn_merge4n<<<4096, 256, 0, stream>>>(lP, aP, go, bgo, out);
    } else {
      attn1<<<512, 128, 0, stream>>>(qws, kws, vtws, go, bgo, out);
    }
  }
}

// Round 19
// 58.038 us; speedup vs baseline: 1.1871x; 1.0179x over previous
//
#include <hip/hip_runtime.h>

#define TT 4096

typedef unsigned short u16;
typedef unsigned int u32;

typedef short bf16x8 __attribute__((ext_vector_type(8)));
typedef float f32x4 __attribute__((ext_vector_type(4)));

union U8 {
  uint2 q[2];
  uint4 u4;
  bf16x8 v;
  short s[8];
  u32 w[4];
};

static __device__ __forceinline__ u16 f2bf(float f) {
  union { float f; u32 u; } cv;
  cv.f = f;
  u32 r = cv.u + 0x7FFFu + ((cv.u >> 16) & 1u);
  return (u16)(r >> 16);
}
static __device__ __forceinline__ u32 pk2(float a, float b) {
  return (u32)f2bf(a) | ((u32)f2bf(b) << 16);
}
static __device__ __forceinline__ float bf2f(u16 h) {
  union { u32 u; float f; } cv;
  cv.u = ((u32)h) << 16;
  return cv.f;
}
static __device__ __forceinline__ float exp2a(float x) {
  float r; asm("v_exp_f32 %0, %1" : "=v"(r) : "v"(x)); return r;
}
static __device__ __forceinline__ u32 cvtpk(float lo, float hi) {
  u32 r; asm("v_cvt_pk_bf16_f32 %0, %1, %2" : "=v"(r) : "v"(lo), "v"(hi)); return r;
}

// ---------------------------------------------------------------------------
// Kernel 0: pack W{q,k,v} into MFMA B-fragment layout, bf16.
// ---------------------------------------------------------------------------
__global__ __launch_bounds__(64)
void wpack(const float* __restrict__ Wq, const float* __restrict__ Wk,
           const float* __restrict__ Wv, u16* __restrict__ wf)
{
  const int g = blockIdx.x;              // 0..47
  const int p = g >> 4, s = (g >> 2) & 3, nt = g & 3;
  const int l = threadIdx.x, lg = l >> 4, l15 = l & 15;
  const float* W = (p == 0) ? Wq : (p == 1) ? Wk : Wv;
  const int n = l15 + 16 * nt;
  U8 o;
#pragma unroll
  for (int j = 0; j < 8; ++j) {
    int k = 32 * s + ((j < 4) ? (4 * lg + j) : (16 + 4 * lg + (j - 4)));
    o.s[j] = (short)f2bf(W[k * 64 + n]);
  }
  *(uint4*)(wf + (size_t)(g * 64 + l) * 8) = o.u4;
}

// ---------------------------------------------------------------------------
// Kernel 1: projections via MFMA + LayerNorm. 768 blocks x 256 thr (4 waves).
// v output transposed via LDS then coalesced b128 stores.
// ---------------------------------------------------------------------------
__global__ __launch_bounds__(256)
void proj_mfma(const float* __restrict__ x, const u16* __restrict__ wf,
               const float* __restrict__ bq, const float* __restrict__ bk,
               const float* __restrict__ bv,
               const float* __restrict__ gq, const float* __restrict__ bgq,
               const float* __restrict__ gk, const float* __restrict__ bgk,
               const float* __restrict__ gv, const float* __restrict__ bgv,
               u16* __restrict__ qo, u16* __restrict__ ko, u16* __restrict__ vto,
               float* __restrict__ out)
{
  __shared__ u16 xs[64 * 130];           // 16.25 KB; staging + v-transpose
  const int bx = blockIdx.x;
  const int xcd = bx & 7, i = bx >> 3;
  const int tile = xcd * 32 + (i & 31);  // 0..255
  const int p = i >> 5;                  // 0..2
  const int rowbase = tile * 64;
  const int t = threadIdx.x;

  {
    const int row = t >> 2, seg = t & 3;
    const float4* src = (const float4*)(x + (size_t)(rowbase + row) * 128 + seg * 32);
    float4 f[8];
#pragma unroll
    for (int q = 0; q < 8; ++q) f[q] = src[q];
    if ((p == 0 && seg < 2) || (p == 1 && seg >= 2)) {
      float4* dst = (float4*)(out + (size_t)(rowbase + row) * 192 + seg * 32);
#pragma unroll
      for (int q = 0; q < 8; ++q) dst[q] = f[q];
    }
    const int base = row * 256 + seg * 64;
    const int swz = (row & 7) << 4;
    char* xb = (char*)xs;
#pragma unroll
    for (int q = 0; q < 4; ++q) {
      uint4 u;
      u.x = pk2(f[2 * q].x, f[2 * q].y);
      u.y = pk2(f[2 * q].z, f[2 * q].w);
      u.z = pk2(f[2 * q + 1].x, f[2 * q + 1].y);
      u.w = pk2(f[2 * q + 1].z, f[2 * q + 1].w);
      *(uint4*)(xb + ((base + 16 * q) ^ swz)) = u;
    }
  }

  const int w = t >> 6, l = t & 63, lg = l >> 4, l15 = l & 15;
  U8 bfr[4][4];
  const u16* wp = wf + (size_t)p * (16 * 64 * 8);
#pragma unroll
  for (int s = 0; s < 4; ++s)
#pragma unroll
    for (int nt = 0; nt < 4; ++nt)
      bfr[s][nt].u4 = *(const uint4*)(wp + ((s * 4 + nt) * 64 + l) * 8);

  __syncthreads();

  f32x4 acc[4];
#pragma unroll
  for (int nt = 0; nt < 4; ++nt) acc[nt] = (f32x4){0.f, 0.f, 0.f, 0.f};
  const int abase = (16 * w + l15) * 256;
  const int aswz = (l15 & 7) << 4;
  const char* xb = (const char*)xs;
#pragma unroll
  for (int s = 0; s < 4; ++s) {
    U8 af;
    af.q[0] = *(const uint2*)(xb + ((abase + s * 64 + 8 * lg) ^ aswz));
    af.q[1] = *(const uint2*)(xb + ((abase + s * 64 + 8 * lg + 32) ^ aswz));
#pragma unroll
    for (int nt = 0; nt < 4; ++nt)
      acc[nt] = __builtin_amdgcn_mfma_f32_16x16x32_bf16(af.v, bfr[s][nt].v, acc[nt], 0, 0, 0);
  }

  const float* bb = (p == 0) ? bq : (p == 1) ? bk : bv;
  const float* gg = (p == 0) ? gq : (p == 1) ? gk : gv;
  const float* hh = (p == 0) ? bgq : (p == 1) ? bgk : bgv;
  float bcol[4], gcol[4], hcol[4];
#pragma unroll
  for (int nt = 0; nt < 4; ++nt) {
    int col = l15 + 16 * nt;
    bcol[nt] = bb[col]; gcol[nt] = gg[col]; hcol[nt] = hh[col];
  }
  float vals[4][4];
#pragma unroll
  for (int nt = 0; nt < 4; ++nt)
#pragma unroll
    for (int r = 0; r < 4; ++r) vals[nt][r] = acc[nt][r] + bcol[nt];

  float s1[4], s2[4];
#pragma unroll
  for (int r = 0; r < 4; ++r) {
    s1[r] = vals[0][r] + vals[1][r] + vals[2][r] + vals[3][r];
    s2[r] = vals[0][r] * vals[0][r] + vals[1][r] * vals[1][r]
          + vals[2][r] * vals[2][r] + vals[3][r] * vals[3][r];
#pragma unroll
    for (int d = 1; d < 16; d <<= 1) {
      s1[r] += __shfl_xor(s1[r], d);
      s2[r] += __shfl_xor(s2[r], d);
    }
  }

  if (p < 2) {
    u16* dst = (p == 0) ? qo : ko;
#pragma unroll
    for (int r = 0; r < 4; ++r) {
      float mu = s1[r] * (1.f / 64.f);
      float var = s2[r] * (1.f / 64.f) - mu * mu;
      float rs = rsqrtf(var + 1e-5f);
      int grow = rowbase + 16 * w + 4 * lg + r;
#pragma unroll
      for (int nt = 0; nt < 4; ++nt)
        dst[(size_t)grow * 64 + l15 + 16 * nt] =
            f2bf((vals[nt][r] - mu) * rs * gcol[nt] + hcol[nt]);
    }
  } else {
    // v: LDS transpose (stride-65 pad) then coalesced stores
    u16* vls = xs;
    __syncthreads();                      // all A-frag reads done
#pragma unroll
    for (int r = 0; r < 4; ++r) {
      float mu = s1[r] * (1.f / 64.f);
      float var = s2[r] * (1.f / 64.f) - mu * mu;
      float rs = rsqrtf(var + 1e-5f);
      int row = 16 * w + 4 * lg + r;
#pragma unroll
      for (int nt = 0; nt < 4; ++nt)
        vls[row * 65 + l15 + 16 * nt] =
            f2bf((vals[nt][r] - mu) * rs * gcol[nt] + hcol[nt]);
    }
    __syncthreads();
    const int b = rowbase >> 12;
    const int tl = rowbase & 4095;
    const int col = t >> 2;               // 0..63
    const int tq = (t & 3) * 16;          // row offset 0,16,32,48
    U8 o0, o1;
#pragma unroll
    for (int i = 0; i < 8; ++i) o0.s[i] = (short)vls[(tq + i) * 65 + col];
#pragma unroll
    for (int i = 0; i < 8; ++i) o1.s[i] = (short)vls[(tq + 8 + i) * 65 + col];
    u16* dst = vto + (size_t)(b * 64 + col) * TT + tl + tq;
    *(uint4*)(dst + 0) = o0.u4;
    *(uint4*)(dst + 8) = o1.u4;
  }
}

// ---------------------------------------------------------------------------
// Kernel 2a: paired-qtile W=4 segment, NO-MAX softmax, branch-free chains.
// Pair {qa=2pr, qb=2pr+1} shares every kf/vf LDS read. One barrier per block.
// Partials: l (f32) + unnormalized acc (bf16); merge is a pure sum.
// A/B vs round-18 banked config: s_setprio REMOVED (only change).
// ---------------------------------------------------------------------------
__global__ __launch_bounds__(256)
void attn_pair4n(const u16* __restrict__ qg, const u16* __restrict__ kg,
                 const u16* __restrict__ vtg,
                 float* __restrict__ lP, u16* __restrict__ aP)
{
  __shared__ u16 kl4[4 * 64 * 64];
  __shared__ u16 vl4[4 * 64 * 64];
  const int bx = blockIdx.x;
  const int xcd = bx & 7, b = xcd >> 1, e2 = xcd & 1;
  const int j = e2 * 136 + (bx >> 3);     // 0..271
  int M = 0;
  while ((M + 1) * (M + 2) <= j) ++M;     // group M = pairs {2M, 2M+1}
  const int ip = j - M * (M + 1);
  const int e = (ip >= M + 1) ? 1 : 0;
  const int s = ip - e * (M + 1);
  const int pr = 2 * M + e;               // pair 0..31
  const int qa = 2 * pr, qb = 2 * pr + 1;
  const int it0 = 4 * s;
  const int it1 = min(it0 + 4, qb + 1);

  const int t = threadIdx.x;
  const int w = t >> 6, l = t & 63;
  const int l15 = l & 15, lg = l >> 4;
  const int swzl = (l15 & 7) << 4;

  const int wbaseA = qa * 64 + 16 * w, wbaseB = qb * 64 + 16 * w;
  const int qrowA = wbaseA + l15, qrowB = wbaseB + l15;
  const u16* qrpA = qg + (size_t)(b * TT + qrowA) * 64;
  const u16* qrpB = qg + (size_t)(b * TT + qrowB) * 64;
  U8 qfA[2], qfB[2];
#pragma unroll
  for (int hh = 0; hh < 2; ++hh) {
    qfA[hh].q[0] = *(const uint2*)(qrpA + 32 * hh + 4 * lg);
    qfA[hh].q[1] = *(const uint2*)(qrpA + 32 * hh + 4 * lg + 16);
    qfB[hh].q[0] = *(const uint2*)(qrpB + 32 * hh + 4 * lg);
    qfB[hh].q[1] = *(const uint2*)(qrpB + 32 * hh + 4 * lg + 16);
  }

  // ---- stage the whole segment (coalesced), one barrier ----
  {
    const int key = t >> 2, part = t & 3;
    const int sbase = key * 128 + part * 32;
    const int ssw = (key & 7) << 4;
    uint4 kr[4][2], vr[4][2];
#pragma unroll
    for (int tt = 0; tt < 4; ++tt) {
      int tile = it0 + tt; if (tile >= it1) tile = it1 - 1;
      const u16* ks = kg + (size_t)(b * TT + tile * 64 + key) * 64 + part * 16;
      kr[tt][0] = ((const uint4*)ks)[0];
      kr[tt][1] = ((const uint4*)ks)[1];
      const u16* vs = vtg + (size_t)(b * 64 + key) * TT + tile * 64 + part * 16;
      vr[tt][0] = ((const uint4*)vs)[0];
      vr[tt][1] = ((const uint4*)vs)[1];
    }
#pragma unroll
    for (int tt = 0; tt < 4; ++tt) {
      char* kd = (char*)kl4 + tt * 8192;
      char* vd = (char*)vl4 + tt * 8192;
      *(uint4*)(kd + ((sbase + 0) ^ ssw)) = kr[tt][0];
      *(uint4*)(kd + ((sbase + 16) ^ ssw)) = kr[tt][1];
      *(uint4*)(vd + ((sbase + 0) ^ ssw)) = vr[tt][0];
      *(uint4*)(vd + ((sbase + 16) ^ ssw)) = vr[tt][1];
    }
  }
  __syncthreads();

  const float C = 0.18033688011112042f;   // log2(e)/sqrt(64)
  float lA = 0.f, lB = 0.f;
  f32x4 accA[4], accB[4];
#pragma unroll
  for (int ct = 0; ct < 4; ++ct) {
    accA[ct] = (f32x4){0.f, 0.f, 0.f, 0.f};
    accB[ct] = (f32x4){0.f, 0.f, 0.f, 0.f};
  }

  int toff = 0;
  for (int it = it0; it < it1; ++it, toff += 8192) {
    const int kb = it * 64;
    const char* kp = (const char*)kl4 + toff;
    const char* vp = (const char*)vl4 + toff;

    // ---- QK for both chains; each kf read feeds 4 MFMAs ----
    f32x4 stA[4], stB[4];
#pragma unroll
    for (int t4 = 0; t4 < 4; ++t4) {
      const int rbase = (16 * t4 + l15) * 128 + 8 * lg;
      U8 kf0, kf1;
      kf0.q[0] = *(const uint2*)(kp + ((rbase + 0) ^ swzl));
      kf0.q[1] = *(const uint2*)(kp + ((rbase + 32) ^ swzl));
      kf1.q[0] = *(const uint2*)(kp + ((rbase + 64) ^ swzl));
      kf1.q[1] = *(const uint2*)(kp + ((rbase + 96) ^ swzl));
      f32x4 dA = {0.f, 0.f, 0.f, 0.f};
      dA = __builtin_amdgcn_mfma_f32_16x16x32_bf16(kf0.v, qfA[0].v, dA, 0, 0, 0);
      dA = __builtin_amdgcn_mfma_f32_16x16x32_bf16(kf1.v, qfA[1].v, dA, 0, 0, 0);
      stA[t4] = dA;
      f32x4 dB = {0.f, 0.f, 0.f, 0.f};
      dB = __builtin_amdgcn_mfma_f32_16x16x32_bf16(kf0.v, qfB[0].v, dB, 0, 0, 0);
      dB = __builtin_amdgcn_mfma_f32_16x16x32_bf16(kf1.v, qfB[1].v, dB, 0, 0, 0);
      stB[t4] = dB;
    }

    // ---- no-max softmax, both chains (independent straight-line code) ----
    float pA[16], pB[16];
    const bool maskA = (kb + 63 > wbaseA);
    if (maskA) {
#pragma unroll
      for (int t4 = 0; t4 < 4; ++t4) {
#pragma unroll
        for (int r = 0; r < 4; ++r) {
          int keyidx = kb + 16 * t4 + 4 * lg + r;
          float e1 = exp2a(stA[t4][r] * C);
          pA[t4 * 4 + r] = (keyidx > qrowA) ? 0.f : e1;
        }
      }
    } else {
#pragma unroll
      for (int t4 = 0; t4 < 4; ++t4) {
#pragma unroll
        for (int r = 0; r < 4; ++r) pA[t4 * 4 + r] = exp2a(stA[t4][r] * C);
      }
    }
    const bool maskB = (kb + 63 > wbaseB);
    if (maskB) {
#pragma unroll
      for (int t4 = 0; t4 < 4; ++t4) {
#pragma unroll
        for (int r = 0; r < 4; ++r) {
          int keyidx = kb + 16 * t4 + 4 * lg + r;
          float e1 = exp2a(stB[t4][r] * C);
          pB[t4 * 4 + r] = (keyidx > qrowB) ? 0.f : e1;
        }
      }
    } else {
#pragma unroll
      for (int t4 = 0; t4 < 4; ++t4) {
#pragma unroll
        for (int r = 0; r < 4; ++r) pB[t4 * 4 + r] = exp2a(stB[t4][r] * C);
      }
    }
    float smA[8], smB[8];
#pragma unroll
    for (int i = 0; i < 8; ++i) {
      smA[i] = pA[2 * i] + pA[2 * i + 1];
      smB[i] = pB[2 * i] + pB[2 * i + 1];
    }
#pragma unroll
    for (int i = 0; i < 4; ++i) {
      smA[i] = smA[2 * i] + smA[2 * i + 1];
      smB[i] = smB[2 * i] + smB[2 * i + 1];
    }
    float rsA = (smA[0] + smA[1]) + (smA[2] + smA[3]);
    float rsB = (smB[0] + smB[1]) + (smB[2] + smB[3]);
    rsA += __shfl_xor(rsA, 16);
    rsB += __shfl_xor(rsB, 16);
    rsA += __shfl_xor(rsA, 32);
    rsB += __shfl_xor(rsB, 32);
    lA += rsA;
    lB += rsB;

    U8 paA[2], paB[2];
#pragma unroll
    for (int u = 0; u < 2; ++u) {
#pragma unroll
      for (int k2 = 0; k2 < 4; ++k2) {
        paA[u].w[k2] = cvtpk(pA[8 * u + 2 * k2], pA[8 * u + 2 * k2 + 1]);
        paB[u].w[k2] = cvtpk(pB[8 * u + 2 * k2], pB[8 * u + 2 * k2 + 1]);
      }
    }

    // ---- PV for both chains; each vf read feeds 2 MFMAs ----
#pragma unroll
    for (int ct = 0; ct < 4; ++ct) {
      const int vb = (16 * ct + l15) * 128 + 8 * lg;
#pragma unroll
      for (int u = 0; u < 2; ++u) {
        U8 vf;
        vf.q[0] = *(const uint2*)(vp + ((vb + 64 * u + 0) ^ swzl));
        vf.q[1] = *(const uint2*)(vp + ((vb + 64 * u + 32) ^ swzl));
        accA[ct] = __builtin_amdgcn_mfma_f32_16x16x32_bf16(paA[u].v, vf.v, accA[ct], 0, 0, 0);
        accB[ct] = __builtin_amdgcn_mfma_f32_16x16x32_bf16(paB[u].v, vf.v, accB[ct], 0, 0, 0);
      }
    }
  }

  // ---- write partials (per-qtile compact slots; merge4n-compatible) ----
  const int jqA = 2 * M * (M + 1) + (2 * e) * (M + 1) + s;
  const int jqB = 2 * M * (M + 1) + (2 * e + 1) * (M + 1) + s;
  const size_t pbA = (size_t)(b * 544 + jqA) * 64;
  const size_t pbB = (size_t)(b * 544 + jqB) * 64;
  if (lg == 0) {
    lP[pbA + 16 * w + l15] = lA;
    lP[pbB + 16 * w + l15] = lB;
  }
#pragma unroll
  for (int ct = 0; ct < 4; ++ct) {
#pragma unroll
    for (int r = 0; r < 4; ++r) {
      int rin = 16 * w + 4 * lg + r;
      aP[(pbA + rin) * 64 + l15 + 16 * ct] = f2bf(accA[ct][r]);
      aP[(pbB + rin) * 64 + l15 + 16 * ct] = f2bf(accB[ct][r]);
    }
  }
}

// ---------------------------------------------------------------------------
// Kernel 2b: merge = pure sum over segments + output LayerNorm.
// ---------------------------------------------------------------------------
__global__ __launch_bounds__(256)
void attn_merge4n(const float* __restrict__ lP, const u16* __restrict__ aP,
                  const float* __restrict__ go, const float* __restrict__ bgo,
                  float* __restrict__ out)
{
  const int t = threadIdx.x;
  const int w = t >> 6, c = t & 63;
  const int row = blockIdx.x * 4 + w;
  const int tid2 = row >> 6, rin = row & 63;
  const int b = tid2 >> 6, q = tid2 & 63;
  const int Q = q >> 2;
  const int base_q = b * 544 + 2 * Q * (Q + 1) + (q & 3) * (Q + 1);
  const int ns = Q + 1;

  float L = 0.f, o = 0.f;
  for (int s = 0; s < ns; ++s) {
    const size_t pb = (size_t)(base_q + s) * 64;
    L += lP[pb + rin];
    o += bf2f(aP[(pb + rin) * 64 + c]);
  }
  o /= L;

  float s1 = o, s2 = o * o;
#pragma unroll
  for (int d = 1; d < 64; d <<= 1) {
    s1 += __shfl_xor(s1, d);
    s2 += __shfl_xor(s2, d);
  }
  float mu = s1 * (1.f / 64.f);
  float var = s2 * (1.f / 64.f) - mu * mu;
  float rs = rsqrtf(var + 1e-5f);
  out[(size_t)row * 192 + 128 + c] = (o - mu) * rs * go[c] + bgo[c];
}

// ---------------------------------------------------------------------------
// Kernel 2 last-resort fallback: single-pass LDS attn (round 2 proven).
// ---------------------------------------------------------------------------
__global__ __launch_bounds__(128)
void attn1(const u16* __restrict__ qg, const u16* __restrict__ kg,
           const u16* __restrict__ vtg,
           const float* __restrict__ go, const float* __restrict__ bgo,
           float* __restrict__ out)
{
  __shared__ u16 kl[64 * 64];
  __shared__ u16 vl[64 * 64];
  const int bx = blockIdx.x;
  const int tt = (bx < 256) ? bx : (767 - bx);
  const int b = tt >> 7;
  const int q0 = (tt & 127) * 32;
  const int tid = threadIdx.x;
  const int w = tid >> 6;
  const int l = tid & 63;
  const int l15 = l & 15;
  const int lg = l >> 4;
  const int swzl = (l15 & 7) << 4;

  const int qrow = q0 + 16 * w + l15;
  const u16* qrp = qg + (size_t)(b * TT + qrow) * 64;
  U8 qf[2];
#pragma unroll
  for (int h = 0; h < 2; ++h) {
    qf[h].q[0] = *(const uint2*)(qrp + 32 * h + 4 * lg);
    qf[h].q[1] = *(const uint2*)(qrp + 32 * h + 4 * lg + 16);
  }

  float m_run = -1e30f, l_run = 0.f;
  f32x4 acc[4];
#pragma unroll
  for (int ct = 0; ct < 4; ++ct) acc[ct] = (f32x4){0.f, 0.f, 0.f, 0.f};

  const int nkv = (q0 >> 6) + 1;
  for (int it = 0; it < nkv; ++it) {
    const int kb = it * 64;
    {
      const int key = tid >> 1;
      const int dh = (tid & 1) * 32;
      const u16* ks = kg + (size_t)(b * TT + kb + key) * 64 + dh;
      uint4 d0 = *(const uint4*)(ks + 0);
      uint4 d1 = *(const uint4*)(ks + 8);
      uint4 d2 = *(const uint4*)(ks + 16);
      uint4 d3 = *(const uint4*)(ks + 24);
      const int base = key * 128 + dh * 2;
      const int sw = (key & 7) << 4;
      char* kd = (char*)kl;
      *(uint4*)(kd + ((base + 0) ^ sw)) = d0;
      *(uint4*)(kd + ((base + 16) ^ sw)) = d1;
      *(uint4*)(kd + ((base + 32) ^ sw)) = d2;
      *(uint4*)(kd + ((base + 48) ^ sw)) = d3;
      const u16* vs = vtg + (size_t)(b * 64 + key) * TT + kb + dh;
      uint4 e0 = *(const uint4*)(vs + 0);
      uint4 e1 = *(const uint4*)(vs + 8);
      uint4 e2 = *(const uint4*)(vs + 16);
      uint4 e3 = *(const uint4*)(vs + 24);
      char* vd = (char*)vl;
      *(uint4*)(vd + ((base + 0) ^ sw)) = e0;
      *(uint4*)(vd + ((base + 16) ^ sw)) = e1;
      *(uint4*)(vd + ((base + 32) ^ sw)) = e2;
      *(uint4*)(vd + ((base + 48) ^ sw)) = e3;
    }
    __syncthreads();

    f32x4 st[4];
#pragma unroll
    for (int t4 = 0; t4 < 4; ++t4) {
      const int rbase = (16 * t4 + l15) * 128 + 8 * lg;
      const char* kp = (const char*)kl;
      U8 kf0, kf1;
      kf0.q[0] = *(const uint2*)(kp + ((rbase + 0) ^ swzl));
      kf0.q[1] = *(const uint2*)(kp + ((rbase + 32) ^ swzl));
      kf1.q[0] = *(const uint2*)(kp + ((rbase + 64) ^ swzl));
      kf1.q[1] = *(const uint2*)(kp + ((rbase + 96) ^ swzl));
      f32x4 d = {0.f, 0.f, 0.f, 0.f};
      d = __builtin_amdgcn_mfma_f32_16x16x32_bf16(kf0.v, qf[0].v, d, 0, 0, 0);
      d = __builtin_amdgcn_mfma_f32_16x16x32_bf16(kf1.v, qf[1].v, d, 0, 0, 0);
      st[t4] = d;
    }

    float sv[16];
    const bool needmask = (kb + 63 > q0 + 16 * w);
#pragma unroll
    for (int t4 = 0; t4 < 4; ++t4) {
#pragma unroll
      for (int r = 0; r < 4; ++r) {
        float sc = st[t4][r] * 0.125f;
        if (needmask) {
          int keyidx = kb + 16 * t4 + 4 * lg + r;
          if (keyidx > qrow) sc = -1e30f;
        }
        sv[t4 * 4 + r] = sc;
      }
    }
    float mt = sv[0];
#pragma unroll
    for (int i = 1; i < 16; ++i) mt = fmaxf(mt, sv[i]);
    mt = fmaxf(mt, __shfl_xor(mt, 16));
    mt = fmaxf(mt, __shfl_xor(mt, 32));
    const float mnew = fmaxf(m_run, mt);
    const float al = __expf(m_run - mnew);
    float p[16];
    float rsum = 0.f;
#pragma unroll
    for (int i = 0; i < 16; ++i) { p[i] = __expf(sv[i] - mnew); rsum += p[i]; }
    rsum += __shfl_xor(rsum, 16);
    rsum += __shfl_xor(rsum, 32);
    l_run = l_run * al + rsum;
    m_run = mnew;
    float ar[4];
#pragma unroll
    for (int r = 0; r < 4; ++r) ar[r] = __shfl(al, 4 * lg + r);
#pragma unroll
    for (int ct = 0; ct < 4; ++ct) {
#pragma unroll
      for (int r = 0; r < 4; ++r) acc[ct][r] *= ar[r];
    }
    U8 pa[2];
#pragma unroll
    for (int u = 0; u < 2; ++u) {
#pragma unroll
      for (int i = 0; i < 8; ++i) pa[u].s[i] = (short)f2bf(p[8 * u + i]);
    }

#pragma unroll
    for (int ct = 0; ct < 4; ++ct) {
      const int vb = (16 * ct + l15) * 128 + 8 * lg;
      const char* vp = (const char*)vl;
#pragma unroll
      for (int u = 0; u < 2; ++u) {
        U8 vf;
        vf.q[0] = *(const uint2*)(vp + ((vb + 64 * u + 0) ^ swzl));
        vf.q[1] = *(const uint2*)(vp + ((vb + 64 * u + 32) ^ swzl));
        acc[ct] = __builtin_amdgcn_mfma_f32_16x16x32_bf16(pa[u].v, vf.v, acc[ct], 0, 0, 0);
      }
    }
    __syncthreads();
  }

  float linv[4];
#pragma unroll
  for (int r = 0; r < 4; ++r) linv[r] = 1.f / __shfl(l_run, 4 * lg + r);
  float o[4][4];
#pragma unroll
  for (int ct = 0; ct < 4; ++ct) {
#pragma unroll
    for (int r = 0; r < 4; ++r) o[ct][r] = acc[ct][r] * linv[r];
  }
  float s1[4], s2[4];
#pragma unroll
  for (int r = 0; r < 4; ++r) {
    s1[r] = o[0][r] + o[1][r] + o[2][r] + o[3][r];
    s2[r] = o[0][r] * o[0][r] + o[1][r] * o[1][r] + o[2][r] * o[2][r] + o[3][r] * o[3][r];
#pragma unroll
    for (int d = 1; d < 16; d <<= 1) {
      s1[r] += __shfl_xor(s1[r], d);
      s2[r] += __shfl_xor(s2[r], d);
    }
  }
  float gov[4], bgv2[4];
#pragma unroll
  for (int ct = 0; ct < 4; ++ct) {
    gov[ct] = go[16 * ct + l15];
    bgv2[ct] = bgo[16 * ct + l15];
  }
#pragma unroll
  for (int r = 0; r < 4; ++r) {
    float mu = s1[r] * (1.f / 64.f);
    float var = s2[r] * (1.f / 64.f) - mu * mu;
    float rs = rsqrtf(var + 1e-5f);
    int row = q0 + 16 * w + 4 * lg + r;
    float* op = out + (size_t)(b * TT + row) * 192 + 128;
#pragma unroll
    for (int ct = 0; ct < 4; ++ct)
      op[16 * ct + l15] = (o[ct][r] - mu) * rs * gov[ct] + bgv2[ct];
  }
}

extern "C" void kernel_launch(void* const* d_in, const int* in_sizes, int n_in,
                              void* d_out, int out_size, void* d_ws, size_t ws_size,
                              hipStream_t stream) {
  (void)in_sizes; (void)n_in; (void)out_size;
  const float* x   = (const float*)d_in[0];
  const float* Wq  = (const float*)d_in[1];
  const float* bq  = (const float*)d_in[2];
  const float* Wk  = (const float*)d_in[3];
  const float* bk  = (const float*)d_in[4];
  const float* Wv  = (const float*)d_in[5];
  const float* bv  = (const float*)d_in[6];
  const float* gq  = (const float*)d_in[7];
  const float* bgq = (const float*)d_in[8];
  const float* gk  = (const float*)d_in[9];
  const float* bgk = (const float*)d_in[10];
  const float* gv  = (const float*)d_in[11];
  const float* bgv = (const float*)d_in[12];
  const float* go  = (const float*)d_in[13];
  const float* bgo = (const float*)d_in[14];
  float* out = (float*)d_out;

  char* wsb = (char*)d_ws;
  u16* qws  = (u16*)wsb;
  u16* kws  = (u16*)(wsb + (2u << 20));
  u16* vtws = (u16*)(wsb + (4u << 20));
  u16* wfr  = (u16*)(wsb + (6u << 20));
  const size_t OFF_LP = (6u << 20) + 65536;

  wpack<<<48, 64, 0, stream>>>(Wq, Wk, Wv, wfr);
  proj_mfma<<<768, 256, 0, stream>>>(x, wfr, bq, bk, bv,
                                     gq, bgq, gk, bgk, gv, bgv,
                                     qws, kws, vtws, out);

  {
    // W=4 paired: 4 batches x 544 qtile-segment slots; l (f32) + acc (bf16)
    const size_t SEG4 = 4u * 544;
    const size_t LPS = SEG4 * 64 * 4;               // 557,056
    const size_t APS = SEG4 * 64 * 64 * 2;          // 17,825,792
    const size_t OFF_AP = OFF_LP + LPS;
    const size_t NEED = OFF_AP + APS;               // ~24.7 MB

    if (ws_size >= NEED) {
      float* lP = (float*)(wsb + OFF_LP);
      u16*   aP = (u16*)(wsb + OFF_AP);
      attn_pair4n<<<1088, 256, 0, stream>>>(qws, kws, vtws, lP, aP);
      attn_merge4n<<<4096, 256, 0, stream>>>(lP, aP, go, bgo, out);
    } else {
      attn1<<<512, 128, 0, stream>>>(qws, kws, vtws, go, bgo, out);
    }
  }
}

// Round 20
// 58.010 us; speedup vs baseline: 1.1876x; 1.0005x over previous
//
#include <hip/hip_runtime.h>

#define TT 4096

typedef unsigned short u16;
typedef unsigned int u32;

typedef short bf16x8 __attribute__((ext_vector_type(8)));
typedef float f32x4 __attribute__((ext_vector_type(4)));

union U8 {
  uint2 q[2];
  uint4 u4;
  bf16x8 v;
  short s[8];
  u32 w[4];
};

static __device__ __forceinline__ u16 f2bf(float f) {
  union { float f; u32 u; } cv;
  cv.f = f;
  u32 r = cv.u + 0x7FFFu + ((cv.u >> 16) & 1u);
  return (u16)(r >> 16);
}
static __device__ __forceinline__ u32 pk2(float a, float b) {
  return (u32)f2bf(a) | ((u32)f2bf(b) << 16);
}
static __device__ __forceinline__ float bf2f(u16 h) {
  union { u32 u; float f; } cv;
  cv.u = ((u32)h) << 16;
  return cv.f;
}
static __device__ __forceinline__ float exp2a(float x) {
  float r; asm("v_exp_f32 %0, %1" : "=v"(r) : "v"(x)); return r;
}
static __device__ __forceinline__ u32 cvtpk(float lo, float hi) {
  u32 r; asm("v_cvt_pk_bf16_f32 %0, %1, %2" : "=v"(r) : "v"(lo), "v"(hi)); return r;
}

// ---------------------------------------------------------------------------
// Kernel 0: pack W{q,k,v} into MFMA B-fragment layout, bf16.
// ---------------------------------------------------------------------------
__global__ __launch_bounds__(64)
void wpack(const float* __restrict__ Wq, const float* __restrict__ Wk,
           const float* __restrict__ Wv, u16* __restrict__ wf)
{
  const int g = blockIdx.x;              // 0..47
  const int p = g >> 4, s = (g >> 2) & 3, nt = g & 3;
  const int l = threadIdx.x, lg = l >> 4, l15 = l & 15;
  const float* W = (p == 0) ? Wq : (p == 1) ? Wk : Wv;
  const int n = l15 + 16 * nt;
  U8 o;
#pragma unroll
  for (int j = 0; j < 8; ++j) {
    int k = 32 * s + ((j < 4) ? (4 * lg + j) : (16 + 4 * lg + (j - 4)));
    o.s[j] = (short)f2bf(W[k * 64 + n]);
  }
  *(uint4*)(wf + (size_t)(g * 64 + l) * 8) = o.u4;
}

// ---------------------------------------------------------------------------
// Kernel 1: projections via MFMA + LayerNorm. 768 blocks x 256 thr (4 waves).
// v output transposed via LDS then coalesced b128 stores.
// ---------------------------------------------------------------------------
__global__ __launch_bounds__(256)
void proj_mfma(const float* __restrict__ x, const u16* __restrict__ wf,
               const float* __restrict__ bq, const float* __restrict__ bk,
               const float* __restrict__ bv,
               const float* __restrict__ gq, const float* __restrict__ bgq,
               const float* __restrict__ gk, const float* __restrict__ bgk,
               const float* __restrict__ gv, const float* __restrict__ bgv,
               u16* __restrict__ qo, u16* __restrict__ ko, u16* __restrict__ vto,
               float* __restrict__ out)
{
  __shared__ u16 xs[64 * 130];           // 16.25 KB; staging + v-transpose
  const int bx = blockIdx.x;
  const int xcd = bx & 7, i = bx >> 3;
  const int tile = xcd * 32 + (i & 31);  // 0..255
  const int p = i >> 5;                  // 0..2
  const int rowbase = tile * 64;
  const int t = threadIdx.x;

  {
    const int row = t >> 2, seg = t & 3;
    const float4* src = (const float4*)(x + (size_t)(rowbase + row) * 128 + seg * 32);
    float4 f[8];
#pragma unroll
    for (int q = 0; q < 8; ++q) f[q] = src[q];
    if ((p == 0 && seg < 2) || (p == 1 && seg >= 2)) {
      float4* dst = (float4*)(out + (size_t)(rowbase + row) * 192 + seg * 32);
#pragma unroll
      for (int q = 0; q < 8; ++q) dst[q] = f[q];
    }
    const int base = row * 256 + seg * 64;
    const int swz = (row & 7) << 4;
    char* xb = (char*)xs;
#pragma unroll
    for (int q = 0; q < 4; ++q) {
      uint4 u;
      u.x = pk2(f[2 * q].x, f[2 * q].y);
      u.y = pk2(f[2 * q].z, f[2 * q].w);
      u.z = pk2(f[2 * q + 1].x, f[2 * q + 1].y);
      u.w = pk2(f[2 * q + 1].z, f[2 * q + 1].w);
      *(uint4*)(xb + ((base + 16 * q) ^ swz)) = u;
    }
  }

  const int w = t >> 6, l = t & 63, lg = l >> 4, l15 = l & 15;
  U8 bfr[4][4];
  const u16* wp = wf + (size_t)p * (16 * 64 * 8);
#pragma unroll
  for (int s = 0; s < 4; ++s)
#pragma unroll
    for (int nt = 0; nt < 4; ++nt)
      bfr[s][nt].u4 = *(const uint4*)(wp + ((s * 4 + nt) * 64 + l) * 8);

  __syncthreads();

  f32x4 acc[4];
#pragma unroll
  for (int nt = 0; nt < 4; ++nt) acc[nt] = (f32x4){0.f, 0.f, 0.f, 0.f};
  const int abase = (16 * w + l15) * 256;
  const int aswz = (l15 & 7) << 4;
  const char* xb = (const char*)xs;
#pragma unroll
  for (int s = 0; s < 4; ++s) {
    U8 af;
    af.q[0] = *(const uint2*)(xb + ((abase + s * 64 + 8 * lg) ^ aswz));
    af.q[1] = *(const uint2*)(xb + ((abase + s * 64 + 8 * lg + 32) ^ aswz));
#pragma unroll
    for (int nt = 0; nt < 4; ++nt)
      acc[nt] = __builtin_amdgcn_mfma_f32_16x16x32_bf16(af.v, bfr[s][nt].v, acc[nt], 0, 0, 0);
  }

  const float* bb = (p == 0) ? bq : (p == 1) ? bk : bv;
  const float* gg = (p == 0) ? gq : (p == 1) ? gk : gv;
  const float* hh = (p == 0) ? bgq : (p == 1) ? bgk : bgv;
  float bcol[4], gcol[4], hcol[4];
#pragma unroll
  for (int nt = 0; nt < 4; ++nt) {
    int col = l15 + 16 * nt;
    bcol[nt] = bb[col]; gcol[nt] = gg[col]; hcol[nt] = hh[col];
  }
  float vals[4][4];
#pragma unroll
  for (int nt = 0; nt < 4; ++nt)
#pragma unroll
    for (int r = 0; r < 4; ++r) vals[nt][r] = acc[nt][r] + bcol[nt];

  float s1[4], s2[4];
#pragma unroll
  for (int r = 0; r < 4; ++r) {
    s1[r] = vals[0][r] + vals[1][r] + vals[2][r] + vals[3][r];
    s2[r] = vals[0][r] * vals[0][r] + vals[1][r] * vals[1][r]
          + vals[2][r] * vals[2][r] + vals[3][r] * vals[3][r];
#pragma unroll
    for (int d = 1; d < 16; d <<= 1) {
      s1[r] += __shfl_xor(s1[r], d);
      s2[r] += __shfl_xor(s2[r], d);
    }
  }

  if (p < 2) {
    u16* dst = (p == 0) ? qo : ko;
#pragma unroll
    for (int r = 0; r < 4; ++r) {
      float mu = s1[r] * (1.f / 64.f);
      float var = s2[r] * (1.f / 64.f) - mu * mu;
      float rs = rsqrtf(var + 1e-5f);
      int grow = rowbase + 16 * w + 4 * lg + r;
#pragma unroll
      for (int nt = 0; nt < 4; ++nt)
        dst[(size_t)grow * 64 + l15 + 16 * nt] =
            f2bf((vals[nt][r] - mu) * rs * gcol[nt] + hcol[nt]);
    }
  } else {
    // v: LDS transpose (stride-65 pad) then coalesced stores
    u16* vls = xs;
    __syncthreads();                      // all A-frag reads done
#pragma unroll
    for (int r = 0; r < 4; ++r) {
      float mu = s1[r] * (1.f / 64.f);
      float var = s2[r] * (1.f / 64.f) - mu * mu;
      float rs = rsqrtf(var + 1e-5f);
      int row = 16 * w + 4 * lg + r;
#pragma unroll
      for (int nt = 0; nt < 4; ++nt)
        vls[row * 65 + l15 + 16 * nt] =
            f2bf((vals[nt][r] - mu) * rs * gcol[nt] + hcol[nt]);
    }
    __syncthreads();
    const int b = rowbase >> 12;
    const int tl = rowbase & 4095;
    const int col = t >> 2;               // 0..63
    const int tq = (t & 3) * 16;          // row offset 0,16,32,48
    U8 o0, o1;
#pragma unroll
    for (int i = 0; i < 8; ++i) o0.s[i] = (short)vls[(tq + i) * 65 + col];
#pragma unroll
    for (int i = 0; i < 8; ++i) o1.s[i] = (short)vls[(tq + 8 + i) * 65 + col];
    u16* dst = vto + (size_t)(b * 64 + col) * TT + tl + tq;
    *(uint4*)(dst + 0) = o0.u4;
    *(uint4*)(dst + 8) = o1.u4;
  }
}

// ---------------------------------------------------------------------------
// Kernel 2a: paired-qtile W=4 segment, NO-MAX softmax, branch-free chains.
// Pair {qa=2pr, qb=2pr+1} shares every kf/vf LDS read. One barrier per block.
// Partials: l (f32) + unnormalized acc (bf16); merge is a pure sum.
// FINAL BANKED CONFIG: round-19 measured best, 58.0 us total.
// ---------------------------------------------------------------------------
__global__ __launch_bounds__(256)
void attn_pair4n(const u16* __restrict__ qg, const u16* __restrict__ kg,
                 const u16* __restrict__ vtg,
                 float* __restrict__ lP, u16* __restrict__ aP)
{
  __shared__ u16 kl4[4 * 64 * 64];
  __shared__ u16 vl4[4 * 64 * 64];
  const int bx = blockIdx.x;
  const int xcd = bx & 7, b = xcd >> 1, e2 = xcd & 1;
  const int j = e2 * 136 + (bx >> 3);     // 0..271
  int M = 0;
  while ((M + 1) * (M + 2) <= j) ++M;     // group M = pairs {2M, 2M+1}
  const int ip = j - M * (M + 1);
  const int e = (ip >= M + 1) ? 1 : 0;
  const int s = ip - e * (M + 1);
  const int pr = 2 * M + e;               // pair 0..31
  const int qa = 2 * pr, qb = 2 * pr + 1;
  const int it0 = 4 * s;
  const int it1 = min(it0 + 4, qb + 1);

  const int t = threadIdx.x;
  const int w = t >> 6, l = t & 63;
  const int l15 = l & 15, lg = l >> 4;
  const int swzl = (l15 & 7) << 4;

  const int wbaseA = qa * 64 + 16 * w, wbaseB = qb * 64 + 16 * w;
  const int qrowA = wbaseA + l15, qrowB = wbaseB + l15;
  const u16* qrpA = qg + (size_t)(b * TT + qrowA) * 64;
  const u16* qrpB = qg + (size_t)(b * TT + qrowB) * 64;
  U8 qfA[2], qfB[2];
#pragma unroll
  for (int hh = 0; hh < 2; ++hh) {
    qfA[hh].q[0] = *(const uint2*)(qrpA + 32 * hh + 4 * lg);
    qfA[hh].q[1] = *(const uint2*)(qrpA + 32 * hh + 4 * lg + 16);
    qfB[hh].q[0] = *(const uint2*)(qrpB + 32 * hh + 4 * lg);
    qfB[hh].q[1] = *(const uint2*)(qrpB + 32 * hh + 4 * lg + 16);
  }

  // ---- stage the whole segment (coalesced), one barrier ----
  {
    const int key = t >> 2, part = t & 3;
    const int sbase = key * 128 + part * 32;
    const int ssw = (key & 7) << 4;
    uint4 kr[4][2], vr[4][2];
#pragma unroll
    for (int tt = 0; tt < 4; ++tt) {
      int tile = it0 + tt; if (tile >= it1) tile = it1 - 1;
      const u16* ks = kg + (size_t)(b * TT + tile * 64 + key) * 64 + part * 16;
      kr[tt][0] = ((const uint4*)ks)[0];
      kr[tt][1] = ((const uint4*)ks)[1];
      const u16* vs = vtg + (size_t)(b * 64 + key) * TT + tile * 64 + part * 16;
      vr[tt][0] = ((const uint4*)vs)[0];
      vr[tt][1] = ((const uint4*)vs)[1];
    }
#pragma unroll
    for (int tt = 0; tt < 4; ++tt) {
      char* kd = (char*)kl4 + tt * 8192;
      char* vd = (char*)vl4 + tt * 8192;
      *(uint4*)(kd + ((sbase + 0) ^ ssw)) = kr[tt][0];
      *(uint4*)(kd + ((sbase + 16) ^ ssw)) = kr[tt][1];
      *(uint4*)(vd + ((sbase + 0) ^ ssw)) = vr[tt][0];
      *(uint4*)(vd + ((sbase + 16) ^ ssw)) = vr[tt][1];
    }
  }
  __syncthreads();

  const float C = 0.18033688011112042f;   // log2(e)/sqrt(64)
  float lA = 0.f, lB = 0.f;
  f32x4 accA[4], accB[4];
#pragma unroll
  for (int ct = 0; ct < 4; ++ct) {
    accA[ct] = (f32x4){0.f, 0.f, 0.f, 0.f};
    accB[ct] = (f32x4){0.f, 0.f, 0.f, 0.f};
  }

  int toff = 0;
  for (int it = it0; it < it1; ++it, toff += 8192) {
    const int kb = it * 64;
    const char* kp = (const char*)kl4 + toff;
    const char* vp = (const char*)vl4 + toff;

    // ---- QK for both chains; each kf read feeds 4 MFMAs ----
    f32x4 stA[4], stB[4];
#pragma unroll
    for (int t4 = 0; t4 < 4; ++t4) {
      const int rbase = (16 * t4 + l15) * 128 + 8 * lg;
      U8 kf0, kf1;
      kf0.q[0] = *(const uint2*)(kp + ((rbase + 0) ^ swzl));
      kf0.q[1] = *(const uint2*)(kp + ((rbase + 32) ^ swzl));
      kf1.q[0] = *(const uint2*)(kp + ((rbase + 64) ^ swzl));
      kf1.q[1] = *(const uint2*)(kp + ((rbase + 96) ^ swzl));
      f32x4 dA = {0.f, 0.f, 0.f, 0.f};
      dA = __builtin_amdgcn_mfma_f32_16x16x32_bf16(kf0.v, qfA[0].v, dA, 0, 0, 0);
      dA = __builtin_amdgcn_mfma_f32_16x16x32_bf16(kf1.v, qfA[1].v, dA, 0, 0, 0);
      stA[t4] = dA;
      f32x4 dB = {0.f, 0.f, 0.f, 0.f};
      dB = __builtin_amdgcn_mfma_f32_16x16x32_bf16(kf0.v, qfB[0].v, dB, 0, 0, 0);
      dB = __builtin_amdgcn_mfma_f32_16x16x32_bf16(kf1.v, qfB[1].v, dB, 0, 0, 0);
      stB[t4] = dB;
    }

    // ---- no-max softmax, both chains (independent straight-line code) ----
    float pA[16], pB[16];
    const bool maskA = (kb + 63 > wbaseA);
    if (maskA) {
#pragma unroll
      for (int t4 = 0; t4 < 4; ++t4) {
#pragma unroll
        for (int r = 0; r < 4; ++r) {
          int keyidx = kb + 16 * t4 + 4 * lg + r;
          float e1 = exp2a(stA[t4][r] * C);
          pA[t4 * 4 + r] = (keyidx > qrowA) ? 0.f : e1;
        }
      }
    } else {
#pragma unroll
      for (int t4 = 0; t4 < 4; ++t4) {
#pragma unroll
        for (int r = 0; r < 4; ++r) pA[t4 * 4 + r] = exp2a(stA[t4][r] * C);
      }
    }
    const bool maskB = (kb + 63 > wbaseB);
    if (maskB) {
#pragma unroll
      for (int t4 = 0; t4 < 4; ++t4) {
#pragma unroll
        for (int r = 0; r < 4; ++r) {
          int keyidx = kb + 16 * t4 + 4 * lg + r;
          float e1 = exp2a(stB[t4][r] * C);
          pB[t4 * 4 + r] = (keyidx > qrowB) ? 0.f : e1;
        }
      }
    } else {
#pragma unroll
      for (int t4 = 0; t4 < 4; ++t4) {
#pragma unroll
        for (int r = 0; r < 4; ++r) pB[t4 * 4 + r] = exp2a(stB[t4][r] * C);
      }
    }
    float smA[8], smB[8];
#pragma unroll
    for (int i = 0; i < 8; ++i) {
      smA[i] = pA[2 * i] + pA[2 * i + 1];
      smB[i] = pB[2 * i] + pB[2 * i + 1];
    }
#pragma unroll
    for (int i = 0; i < 4; ++i) {
      smA[i] = smA[2 * i] + smA[2 * i + 1];
      smB[i] = smB[2 * i] + smB[2 * i + 1];
    }
    float rsA = (smA[0] + smA[1]) + (smA[2] + smA[3]);
    float rsB = (smB[0] + smB[1]) + (smB[2] + smB[3]);
    rsA += __shfl_xor(rsA, 16);
    rsB += __shfl_xor(rsB, 16);
    rsA += __shfl_xor(rsA, 32);
    rsB += __shfl_xor(rsB, 32);
    lA += rsA;
    lB += rsB;

    U8 paA[2], paB[2];
#pragma unroll
    for (int u = 0; u < 2; ++u) {
#pragma unroll
      for (int k2 = 0; k2 < 4; ++k2) {
        paA[u].w[k2] = cvtpk(pA[8 * u + 2 * k2], pA[8 * u + 2 * k2 + 1]);
        paB[u].w[k2] = cvtpk(pB[8 * u + 2 * k2], pB[8 * u + 2 * k2 + 1]);
      }
    }

    // ---- PV for both chains; each vf read feeds 2 MFMAs ----
#pragma unroll
    for (int ct = 0; ct < 4; ++ct) {
      const int vb = (16 * ct + l15) * 128 + 8 * lg;
#pragma unroll
      for (int u = 0; u < 2; ++u) {
        U8 vf;
        vf.q[0] = *(const uint2*)(vp + ((vb + 64 * u + 0) ^ swzl));
        vf.q[1] = *(const uint2*)(vp + ((vb + 64 * u + 32) ^ swzl));
        accA[ct] = __builtin_amdgcn_mfma_f32_16x16x32_bf16(paA[u].v, vf.v, accA[ct], 0, 0, 0);
        accB[ct] = __builtin_amdgcn_mfma_f32_16x16x32_bf16(paB[u].v, vf.v, accB[ct], 0, 0, 0);
      }
    }
  }

  // ---- write partials (per-qtile compact slots; merge4n-compatible) ----
  const int jqA = 2 * M * (M + 1) + (2 * e) * (M + 1) + s;
  const int jqB = 2 * M * (M + 1) + (2 * e + 1) * (M + 1) + s;
  const size_t pbA = (size_t)(b * 544 + jqA) * 64;
  const size_t pbB = (size_t)(b * 544 + jqB) * 64;
  if (lg == 0) {
    lP[pbA + 16 * w + l15] = lA;
    lP[pbB + 16 * w + l15] = lB;
  }
#pragma unroll
  for (int ct = 0; ct < 4; ++ct) {
#pragma unroll
    for (int r = 0; r < 4; ++r) {
      int rin = 16 * w + 4 * lg + r;
      aP[(pbA + rin) * 64 + l15 + 16 * ct] = f2bf(accA[ct][r]);
      aP[(pbB + rin) * 64 + l15 + 16 * ct] = f2bf(accB[ct][r]);
    }
  }
}

// ---------------------------------------------------------------------------
// Kernel 2b: merge = pure sum over segments + output LayerNorm.
// ---------------------------------------------------------------------------
__global__ __launch_bounds__(256)
void attn_merge4n(const float* __restrict__ lP, const u16* __restrict__ aP,
                  const float* __restrict__ go, const float* __restrict__ bgo,
                  float* __restrict__ out)
{
  const int t = threadIdx.x;
  const int w = t >> 6, c = t & 63;
  const int row = blockIdx.x * 4 + w;
  const int tid2 = row >> 6, rin = row & 63;
  const int b = tid2 >> 6, q = tid2 & 63;
  const int Q = q >> 2;
  const int base_q = b * 544 + 2 * Q * (Q + 1) + (q & 3) * (Q + 1);
  const int ns = Q + 1;

  float L = 0.f, o = 0.f;
  for (int s = 0; s < ns; ++s) {
    const size_t pb = (size_t)(base_q + s) * 64;
    L += lP[pb + rin];
    o += bf2f(aP[(pb + rin) * 64 + c]);
  }
  o /= L;

  float s1 = o, s2 = o * o;
#pragma unroll
  for (int d = 1; d < 64; d <<= 1) {
    s1 += __shfl_xor(s1, d);
    s2 += __shfl_xor(s2, d);
  }
  float mu = s1 * (1.f / 64.f);
  float var = s2 * (1.f / 64.f) - mu * mu;
  float rs = rsqrtf(var + 1e-5f);
  out[(size_t)row * 192 + 128 + c] = (o - mu) * rs * go[c] + bgo[c];
}

// ---------------------------------------------------------------------------
// Kernel 2 last-resort fallback: single-pass LDS attn (round 2 proven).
// ---------------------------------------------------------------------------
__global__ __launch_bounds__(128)
void attn1(const u16* __restrict__ qg, const u16* __restrict__ kg,
           const u16* __restrict__ vtg,
           const float* __restrict__ go, const float* __restrict__ bgo,
           float* __restrict__ out)
{
  __shared__ u16 kl[64 * 64];
  __shared__ u16 vl[64 * 64];
  const int bx = blockIdx.x;
  const int tt = (bx < 256) ? bx : (767 - bx);
  const int b = tt >> 7;
  const int q0 = (tt & 127) * 32;
  const int tid = threadIdx.x;
  const int w = tid >> 6;
  const int l = tid & 63;
  const int l15 = l & 15;
  const int lg = l >> 4;
  const int swzl = (l15 & 7) << 4;

  const int qrow = q0 + 16 * w + l15;
  const u16* qrp = qg + (size_t)(b * TT + qrow) * 64;
  U8 qf[2];
#pragma unroll
  for (int h = 0; h < 2; ++h) {
    qf[h].q[0] = *(const uint2*)(qrp + 32 * h + 4 * lg);
    qf[h].q[1] = *(const uint2*)(qrp + 32 * h + 4 * lg + 16);
  }

  float m_run = -1e30f, l_run = 0.f;
  f32x4 acc[4];
#pragma unroll
  for (int ct = 0; ct < 4; ++ct) acc[ct] = (f32x4){0.f, 0.f, 0.f, 0.f};

  const int nkv = (q0 >> 6) + 1;
  for (int it = 0; it < nkv; ++it) {
    const int kb = it * 64;
    {
      const int key = tid >> 1;
      const int dh = (tid & 1) * 32;
      const u16* ks = kg + (size_t)(b * TT + kb + key) * 64 + dh;
      uint4 d0 = *(const uint4*)(ks + 0);
      uint4 d1 = *(const uint4*)(ks + 8);
      uint4 d2 = *(const uint4*)(ks + 16);
      uint4 d3 = *(const uint4*)(ks + 24);
      const int base = key * 128 + dh * 2;
      const int sw = (key & 7) << 4;
      char* kd = (char*)kl;
      *(uint4*)(kd + ((base + 0) ^ sw)) = d0;
      *(uint4*)(kd + ((base + 16) ^ sw)) = d1;
      *(uint4*)(kd + ((base + 32) ^ sw)) = d2;
      *(uint4*)(kd + ((base + 48) ^ sw)) = d3;
      const u16* vs = vtg + (size_t)(b * 64 + key) * TT + kb + dh;
      uint4 e0 = *(const uint4*)(vs + 0);
      uint4 e1 = *(const uint4*)(vs + 8);
      uint4 e2 = *(const uint4*)(vs + 16);
      uint4 e3 = *(const uint4*)(vs + 24);
      char* vd = (char*)vl;
      *(uint4*)(vd + ((base + 0) ^ sw)) = e0;
      *(uint4*)(vd + ((base + 16) ^ sw)) = e1;
      *(uint4*)(vd + ((base + 32) ^ sw)) = e2;
      *(uint4*)(vd + ((base + 48) ^ sw)) = e3;
    }
    __syncthreads();

    f32x4 st[4];
#pragma unroll
    for (int t4 = 0; t4 < 4; ++t4) {
      const int rbase = (16 * t4 + l15) * 128 + 8 * lg;
      const char* kp = (const char*)kl;
      U8 kf0, kf1;
      kf0.q[0] = *(const uint2*)(kp + ((rbase + 0) ^ swzl));
      kf0.q[1] = *(const uint2*)(kp + ((rbase + 32) ^ swzl));
      kf1.q[0] = *(const uint2*)(kp + ((rbase + 64) ^ swzl));
      kf1.q[1] = *(const uint2*)(kp + ((rbase + 96) ^ swzl));
      f32x4 d = {0.f, 0.f, 0.f, 0.f};
      d = __builtin_amdgcn_mfma_f32_16x16x32_bf16(kf0.v, qf[0].v, d, 0, 0, 0);
      d = __builtin_amdgcn_mfma_f32_16x16x32_bf16(kf1.v, qf[1].v, d, 0, 0, 0);
      st[t4] = d;
    }

    float sv[16];
    const bool needmask = (kb + 63 > q0 + 16 * w);
#pragma unroll
    for (int t4 = 0; t4 < 4; ++t4) {
#pragma unroll
      for (int r = 0; r < 4; ++r) {
        float sc = st[t4][r] * 0.125f;
        if (needmask) {
          int keyidx = kb + 16 * t4 + 4 * lg + r;
          if (keyidx > qrow) sc = -1e30f;
        }
        sv[t4 * 4 + r] = sc;
      }
    }
    float mt = sv[0];
#pragma unroll
    for (int i = 1; i < 16; ++i) mt = fmaxf(mt, sv[i]);
    mt = fmaxf(mt, __shfl_xor(mt, 16));
    mt = fmaxf(mt, __shfl_xor(mt, 32));
    const float mnew = fmaxf(m_run, mt);
    const float al = __expf(m_run - mnew);
    float p[16];
    float rsum = 0.f;
#pragma unroll
    for (int i = 0; i < 16; ++i) { p[i] = __expf(sv[i] - mnew); rsum += p[i]; }
    rsum += __shfl_xor(rsum, 16);
    rsum += __shfl_xor(rsum, 32);
    l_run = l_run * al + rsum;
    m_run = mnew;
    float ar[4];
#pragma unroll
    for (int r = 0; r < 4; ++r) ar[r] = __shfl(al, 4 * lg + r);
#pragma unroll
    for (int ct = 0; ct < 4; ++ct) {
#pragma unroll
      for (int r = 0; r < 4; ++r) acc[ct][r] *= ar[r];
    }
    U8 pa[2];
#pragma unroll
    for (int u = 0; u < 2; ++u) {
#pragma unroll
      for (int i = 0; i < 8; ++i) pa[u].s[i] = (short)f2bf(p[8 * u + i]);
    }

#pragma unroll
    for (int ct = 0; ct < 4; ++ct) {
      const int vb = (16 * ct + l15) * 128 + 8 * lg;
      const char* vp = (const char*)vl;
#pragma unroll
      for (int u = 0; u < 2; ++u) {
        U8 vf;
        vf.q[0] = *(const uint2*)(vp + ((vb + 64 * u + 0) ^ swzl));
        vf.q[1] = *(const uint2*)(vp + ((vb + 64 * u + 32) ^ swzl));
        acc[ct] = __builtin_amdgcn_mfma_f32_16x16x32_bf16(pa[u].v, vf.v, acc[ct], 0, 0, 0);
      }
    }
    __syncthreads();
  }

  float linv[4];
#pragma unroll
  for (int r = 0; r < 4; ++r) linv[r] = 1.f / __shfl(l_run, 4 * lg + r);
  float o[4][4];
#pragma unroll
  for (int ct = 0; ct < 4; ++ct) {
#pragma unroll
    for (int r = 0; r < 4; ++r) o[ct][r] = acc[ct][r] * linv[r];
  }
  float s1[4], s2[4];
#pragma unroll
  for (int r = 0; r < 4; ++r) {
    s1[r] = o[0][r] + o[1][r] + o[2][r] + o[3][r];
    s2[r] = o[0][r] * o[0][r] + o[1][r] * o[1][r] + o[2][r] * o[2][r] + o[3][r] * o[3][r];
#pragma unroll
    for (int d = 1; d < 16; d <<= 1) {
      s1[r] += __shfl_xor(s1[r], d);
      s2[r] += __shfl_xor(s2[r], d);
    }
  }
  float gov[4], bgv2[4];
#pragma unroll
  for (int ct = 0; ct < 4; ++ct) {
    gov[ct] = go[16 * ct + l15];
    bgv2[ct] = bgo[16 * ct + l15];
  }
#pragma unroll
  for (int r = 0; r < 4; ++r) {
    float mu = s1[r] * (1.f / 64.f);
    float var = s2[r] * (1.f / 64.f) - mu * mu;
    float rs = rsqrtf(var + 1e-5f);
    int row = q0 + 16 * w + 4 * lg + r;
    float* op = out + (size_t)(b * TT + row) * 192 + 128;
#pragma unroll
    for (int ct = 0; ct < 4; ++ct)
      op[16 * ct + l15] = (o[ct][r] - mu) * rs * gov[ct] + bgv2[ct];
  }
}

extern "C" void kernel_launch(void* const* d_in, const int* in_sizes, int n_in,
                              void* d_out, int out_size, void* d_ws, size_t ws_size,
                              hipStream_t stream) {
  (void)in_sizes; (void)n_in; (void)out_size;
  const float* x   = (const float*)d_in[0];
  const float* Wq  = (const float*)d_in[1];
  const float* bq  = (const float*)d_in[2];
  const float* Wk  = (const float*)d_in[3];
  const float* bk  = (const float*)d_in[4];
  const float* Wv  = (const float*)d_in[5];
  const float* bv  = (const float*)d_in[6];
  const float* gq  = (const float*)d_in[7];
  const float* bgq = (const float*)d_in[8];
  const float* gk  = (const float*)d_in[9];
  const float* bgk = (const float*)d_in[10];
  const float* gv  = (const float*)d_in[11];
  const float* bgv = (const float*)d_in[12];
  const float* go  = (const float*)d_in[13];
  const float* bgo = (const float*)d_in[14];
  float* out = (float*)d_out;

  char* wsb = (char*)d_ws;
  u16* qws  = (u16*)wsb;
  u16* kws  = (u16*)(wsb + (2u << 20));
  u16* vtws = (u16*)(wsb + (4u << 20));
  u16* wfr  = (u16*)(wsb + (6u << 20));
  const size_t OFF_LP = (6u << 20) + 65536;

  wpack<<<48, 64, 0, stream>>>(Wq, Wk, Wv, wfr);
  proj_mfma<<<768, 256, 0, stream>>>(x, wfr, bq, bk, bv,
                                     gq, bgq, gk, bgk, gv, bgv,
                                     qws, kws, vtws, out);

  {
    // W=4 paired: 4 batches x 544 qtile-segment slots; l (f32) + acc (bf16)
    const size_t SEG4 = 4u * 544;
    const size_t LPS = SEG4 * 64 * 4;               // 557,056
    const size_t APS = SEG4 * 64 * 64 * 2;          // 17,825,792
    const size_t OFF_AP = OFF_LP + LPS;
    const size_t NEED = OFF_AP + APS;               // ~24.7 MB

    if (ws_size >= NEED) {
      float* lP = (float*)(wsb + OFF_LP);
      u16*   aP = (u16*)(wsb + OFF_AP);
      attn_pair4n<<<1088, 256, 0, stream>>>(qws, kws, vtws, lP, aP);
      attn_merge4n<<<4096, 256, 0, stream>>>(lP, aP, go, bgo, out);
    } else {
      attn1<<<512, 128, 0, stream>>>(qws, kws, vtws, go, bgo, out);
    }
  }
}